// Round 1
// baseline (2923.822 us; speedup 1.0000x reference)
//
#include <hip/hip_runtime.h>
#include <math.h>

// ---------------------------------------------------------------------------
// Problem constants: B=16, DIM=256, H=W=64, HEADS=8, C2=16, CF=9, DC=64
// N_SP = H*W = 4096 tokens per batch, channel-major (NCHW) layout everywhere.
// ---------------------------------------------------------------------------

__device__ __forceinline__ float gelu_f(float v) {
    return 0.5f * v * (1.0f + erff(v * 0.70710678118654752440f));
}

// ---------------------------------------------------------------------------
// Generic 1x1-conv GEMM over tokens:  out[b,o,n] = act( sum_c W[row(o), coff+c] * in[b,c,n] + bias[o] ) (+ addsrc / += out)
// in channels are the concat of in1 (c1 channels) and in2 (K-c1 channels).
// rowmap=1 applies the qkv row selection: row = 256*(o/128) + 32*((o%128)/16) + 16 + o%16
// Tile: 64 o x 64 n per block, 256 threads, 4x4 micro-tile, K-chunks of 32.
// ---------------------------------------------------------------------------
__global__ __launch_bounds__(256) void gemm1x1(
    const float* __restrict__ in1, long bs1, int c1,
    const float* __restrict__ in2, long bs2,
    const float* __restrict__ W, int w_ld, int w_col_off, int rowmap,
    const float* __restrict__ bias, const float* __restrict__ addsrc, long bs_add,
    int accum, int do_gelu,
    float* __restrict__ out, long bs_out, int K)
{
    __shared__ float Wt[32][68];
    __shared__ float It[32][68];
    const int t  = threadIdx.x;
    const int b  = blockIdx.z;
    const int n0 = blockIdx.x * 64;
    const int o0 = blockIdx.y * 64;
    const int ty = t >> 4, tx = t & 15;

    float acc[4][4];
#pragma unroll
    for (int i = 0; i < 4; i++)
#pragma unroll
        for (int j = 0; j < 4; j++) acc[i][j] = 0.f;

    const float* i1b = in1 + (long)b * bs1;
    const float* i2b = in2 ? (in2 + (long)b * bs2) : nullptr;

    for (int kk = 0; kk < K; kk += 32) {
        __syncthreads();
        // --- load W tile: Wt[k][o_local] ---
#pragma unroll
        for (int i = 0; i < 8; i++) {
            int e  = i * 256 + t;
            int ol = e >> 5, kc = e & 31;
            int o  = o0 + ol;
            int row = o;
            if (rowmap) row = ((o >> 7) << 8) + (((o >> 4) & 7) << 5) + 16 + (o & 15);
            Wt[kc][ol] = W[(long)row * w_ld + w_col_off + kk + kc];
        }
        // --- load input tile: It[k][n_local] ---
#pragma unroll
        for (int i = 0; i < 8; i++) {
            int e  = i * 256 + t;
            int kr = e >> 6, nl = e & 63;
            int c  = kk + kr;
            const float* src = (c < c1) ? (i1b + (long)c * 4096)
                                        : (i2b + (long)(c - c1) * 4096);
            It[kr][nl] = src[n0 + nl];
        }
        __syncthreads();
#pragma unroll
        for (int k = 0; k < 32; k++) {
            float a4[4], b4[4];
            *(float4*)a4 = *(const float4*)&Wt[k][ty * 4];
            *(float4*)b4 = *(const float4*)&It[k][tx * 4];
#pragma unroll
            for (int i = 0; i < 4; i++)
#pragma unroll
                for (int j = 0; j < 4; j++) acc[i][j] += a4[i] * b4[j];
        }
    }

    // --- epilogue ---
#pragma unroll
    for (int i = 0; i < 4; i++) {
        int o = o0 + ty * 4 + i;
        float bv = bias ? bias[o] : 0.f;
        float v0 = acc[i][0] + bv, v1 = acc[i][1] + bv, v2 = acc[i][2] + bv, v3 = acc[i][3] + bv;
        if (do_gelu) { v0 = gelu_f(v0); v1 = gelu_f(v1); v2 = gelu_f(v2); v3 = gelu_f(v3); }
        long idx = (long)b * bs_out + (long)o * 4096 + n0 + tx * 4;
        if (addsrc) {
            const float4 a = *(const float4*)&addsrc[(long)b * bs_add + (long)o * 4096 + n0 + tx * 4];
            v0 += a.x; v1 += a.y; v2 += a.z; v3 += a.w;
        }
        if (accum) {
            const float4 old = *(const float4*)&out[idx];
            v0 += old.x; v1 += old.y; v2 += old.z; v3 += old.w;
        }
        float4 r; r.x = v0; r.y = v1; r.z = v2; r.w = v3;
        *(float4*)&out[idx] = r;
    }
}

// ---------------------------------------------------------------------------
// Direct KxK conv (SAME, zero-pad) on 64 input channels -> 64 output channels.
// Grid: (16 spatial tiles of 16x16, 4 oc-groups of 16, B). 256 threads.
// Input channels staged in LDS in two halves of 32.
// ---------------------------------------------------------------------------
template<int K>
__global__ __launch_bounds__(256) void conv_small(
    const float* __restrict__ in, long bs_in,
    const float* __restrict__ w, float* __restrict__ out)
{
    constexpr int R  = K / 2;
    constexpr int TW = 16 + 2 * R;
    __shared__ float lds[32 * TW * TW];
    const int t    = threadIdx.x;
    const int tile = blockIdx.x, ocg = blockIdx.y, b = blockIdx.z;
    const int ty0  = (tile >> 2) << 4, tx0 = (tile & 3) << 4;
    const int ty   = t >> 4, tx = t & 15;

    float acc[16];
#pragma unroll
    for (int i = 0; i < 16; i++) acc[i] = 0.f;

    const float* inb = in + (long)b * bs_in;

    for (int ich = 0; ich < 2; ich++) {
        __syncthreads();
        for (int e = t; e < 32 * TW * TW; e += 256) {
            int icl = e / (TW * TW);
            int rem = e % (TW * TW);
            int yy  = rem / TW + ty0 - R;
            int xx  = rem % TW + tx0 - R;
            float v = 0.f;
            if (yy >= 0 && yy < 64 && xx >= 0 && xx < 64)
                v = inb[(long)(ich * 32 + icl) * 4096 + yy * 64 + xx];
            lds[e] = v;
        }
        __syncthreads();
#pragma unroll 1
        for (int icl = 0; icl < 32; icl++) {
            const float* wp = w + ((long)(ocg * 16) * 64 + (ich * 32 + icl)) * (K * K);
#pragma unroll
            for (int ky = 0; ky < K; ky++)
#pragma unroll
                for (int kx = 0; kx < K; kx++) {
                    float v = lds[icl * TW * TW + (ty + ky) * TW + (tx + kx)];
#pragma unroll
                    for (int oc = 0; oc < 16; oc++)
                        acc[oc] += wp[(long)oc * 64 * K * K + ky * K + kx] * v;
                }
        }
    }
    long ob = (long)b * 262144 + (long)(ocg * 16) * 4096 + (ty0 + ty) * 64 + (tx0 + tx);
#pragma unroll
    for (int oc = 0; oc < 16; oc++) out[ob + (long)oc * 4096] = acc[oc];
}

// ---------------------------------------------------------------------------
// Attention per (b,h): one block of 256 threads per (b,h) (128 blocks).
// qkv layout: [b][384][4096]; rows 0..127 = Q (16h+c), 128..255 = K, 256..383 = V.
// Pass 1: accumulate raw S1=q.k^T (16x16), Sf=qf.kf^T (9x9 complex, no conj),
//         and the row sum-squares needed for l2norm (norms are per-row scalars,
//         so normalization commutes with the bilinear dot products).
// Pass 2: softmax-weighted combine with v / rfft(v), irfft closed form.
// Writes ax[b][256][4096]: channels 0..127 = lx, 128..255 = out1.
// ---------------------------------------------------------------------------
#define NC 128
#define ST 132

__global__ __launch_bounds__(256) void attn_kernel(
    const float* __restrict__ qkv,
    const float* __restrict__ temp1, const float* __restrict__ temp2,
    const float* __restrict__ tw1, const float* __restrict__ tw2,
    float* __restrict__ ax)
{
    const int bh = blockIdx.x;
    const int b = bh >> 3, h = bh & 7;
    const int t = threadIdx.x;

    __shared__ float qch[16][ST], kch[16][ST];
    __shared__ float qfr[9][ST], qfi[9][ST], kfr[9][ST], kfi[9][ST];
    __shared__ float ct[9][16], st_[9][16];
    __shared__ float S1[16][16], Sfr[9][9], Sfi[9][9];
    __shared__ float qss[16], kss[16], qfss[9], kfss[9];
    __shared__ float attn1[16][16], ar2[9][9], ai2[9][9];

    if (t < 144) {
        int f = t / 16, c = t % 16;
        float ang = 6.283185307179586f * (float)(f * c) / 16.0f;
        ct[f][c] = cosf(ang);
        st_[f][c] = sinf(ang);
    }

    const float* qbase = qkv + (long)b * 1572864 + (long)(16 * h) * 4096;
    const float* kbase = qbase + 128 * 4096;
    const float* vbase = qbase + 256 * 4096;

    float s1 = 0.f, sfr = 0.f, sfi = 0.f;
    float qssp = 0.f, kssp = 0.f, qfssp = 0.f, kfssp = 0.f;
    const int c0 = t >> 4, d0 = t & 15;
    const int cf = t / 9, df = t % 9;   // valid for t < 81
    const int rr = t >> 4, jj0 = t & 15;

    for (int n0 = 0; n0 < 4096; n0 += NC) {
        __syncthreads();
#pragma unroll
        for (int i = 0; i < 8; i++) {
            int e = i * 256 + t, row = e >> 7, nn = e & 127;
            qch[row][nn] = qbase[(long)row * 4096 + n0 + nn];
            kch[row][nn] = kbase[(long)row * 4096 + n0 + nn];
        }
        __syncthreads();
        // rfft along the 16-channel axis: threads 0..127 handle q columns, 128..255 k columns
        {
            int col = t & 127;
            bool isq = t < 128;
            float vv[16];
#pragma unroll
            for (int c = 0; c < 16; c++) vv[c] = isq ? qch[c][col] : kch[c][col];
#pragma unroll
            for (int f = 0; f < 9; f++) {
                float ar = 0.f, ai = 0.f;
#pragma unroll
                for (int c = 0; c < 16; c++) { ar += vv[c] * ct[f][c]; ai -= vv[c] * st_[f][c]; }
                if (isq) { qfr[f][col] = ar; qfi[f][col] = ai; }
                else     { kfr[f][col] = ar; kfi[f][col] = ai; }
            }
        }
        // raw S1[c0][d0] over this chunk
#pragma unroll 4
        for (int n = 0; n < NC; n++) s1 += qch[c0][n] * kch[d0][n];
        // sum-squares partials
        for (int n = jj0; n < NC; n += 16) {
            float a = qch[rr][n]; qssp += a * a;
            float bq = kch[rr][n]; kssp += bq * bq;
        }
        __syncthreads();
        if (t < 81) {
#pragma unroll 4
            for (int n = 0; n < NC; n++) {
                float qr = qfr[cf][n], qi = qfi[cf][n];
                float kr = kfr[df][n], ki = kfi[df][n];
                sfr += qr * kr - qi * ki;
                sfi += qr * ki + qi * kr;
            }
        }
        if (t < 144) {
            int f = t >> 4;
            for (int n = jj0; n < NC; n += 16) {
                qfssp += qfr[f][n] * qfr[f][n] + qfi[f][n] * qfi[f][n];
                kfssp += kfr[f][n] * kfr[f][n] + kfi[f][n] * kfi[f][n];
            }
        }
    }
    __syncthreads();
    S1[c0][d0] = s1;
    if (t < 81) { Sfr[cf][df] = sfr; Sfi[cf][df] = sfi; }
#pragma unroll
    for (int off = 8; off; off >>= 1) {
        qssp  += __shfl_xor(qssp, off);
        kssp  += __shfl_xor(kssp, off);
        qfssp += __shfl_xor(qfssp, off);
        kfssp += __shfl_xor(kfssp, off);
    }
    if (jj0 == 0) { qss[rr] = qssp; kss[rr] = kssp; }
    if (jj0 == 0 && t < 144) { qfss[rr] = qfssp; kfss[rr] = kfssp; }
    __syncthreads();

    const float t1s = temp1[h], t2s = temp2[h];
    if (t < 16) {
        int c = t;
        float nq = fmaxf(sqrtf(qss[c]), 1e-12f);
        float vals[16];
        float m = -1e30f;
#pragma unroll
        for (int d = 0; d < 16; d++) {
            float nk = fmaxf(sqrtf(kss[d]), 1e-12f);
            float v = S1[c][d] / (nq * nk) * t1s;
            vals[d] = v; m = fmaxf(m, v);
        }
        float s = 0.f;
#pragma unroll
        for (int d = 0; d < 16; d++) { vals[d] = expf(vals[d] - m); s += vals[d]; }
#pragma unroll
        for (int d = 0; d < 16; d++)
            attn1[c][d] = vals[d] / s * tw2[(h * 16 + c) * 16 + d];
    }
    if (t >= 32 && t < 41) {
        int c = t - 32;
        float nq = fmaxf(sqrtf(qfss[c]), 1e-12f);
        float vr[9], vi[9];
        float mr = -1e30f, mi = -1e30f;
#pragma unroll
        for (int d = 0; d < 9; d++) {
            float nk = fmaxf(sqrtf(kfss[d]), 1e-12f);
            float sc = t2s / (nq * nk);
            vr[d] = Sfr[c][d] * sc; vi[d] = Sfi[c][d] * sc;
            mr = fmaxf(mr, vr[d]); mi = fmaxf(mi, vi[d]);
        }
        float sr = 0.f, si = 0.f;
#pragma unroll
        for (int d = 0; d < 9; d++) {
            vr[d] = expf(vr[d] - mr); sr += vr[d];
            vi[d] = expf(vi[d] - mi); si += vi[d];
        }
#pragma unroll
        for (int d = 0; d < 9; d++) {
            float tw = tw1[(h * 9 + c) * 9 + d];
            ar2[c][d] = vr[d] / sr * tw;
            ai2[c][d] = vi[d] / si * tw;
        }
    }
    __syncthreads();

    // ---- output pass: out1 = attn1 @ v ; lx = irfft( a @ rfft(v) ) ----
    for (int n0 = 0; n0 < 4096; n0 += NC) {
        __syncthreads();
#pragma unroll
        for (int i = 0; i < 8; i++) {
            int e = i * 256 + t, row = e >> 7, nn = e & 127;
            qch[row][nn] = vbase[(long)row * 4096 + n0 + nn]; // reuse qch as v chunk
        }
        __syncthreads();
        if (t < 128) {
            int col = t;
            float vv[16];
#pragma unroll
            for (int c = 0; c < 16; c++) vv[c] = qch[c][col];
            float o1[16];
#pragma unroll
            for (int m = 0; m < 16; m++) {
                float a = 0.f;
#pragma unroll
                for (int d = 0; d < 16; d++) a += attn1[m][d] * vv[d];
                o1[m] = a;
            }
            float vfr[9], vfi[9];
#pragma unroll
            for (int f = 0; f < 9; f++) {
                float ar = 0.f, ai = 0.f;
#pragma unroll
                for (int c = 0; c < 16; c++) { ar += vv[c] * ct[f][c]; ai -= vv[c] * st_[f][c]; }
                vfr[f] = ar; vfi[f] = ai;
            }
            float Lr[9], Li[9];
#pragma unroll
            for (int c = 0; c < 9; c++) {
                float lr = 0.f, li = 0.f;
#pragma unroll
                for (int d = 0; d < 9; d++) {
                    lr += ar2[c][d] * vfr[d] - ai2[c][d] * vfi[d];
                    li += ar2[c][d] * vfi[d] + ai2[c][d] * vfr[d];
                }
                Lr[c] = lr; Li[c] = li;
            }
            long obase = (long)b * 1048576 + n0 + col;
#pragma unroll
            for (int m = 0; m < 16; m++) {
                float s = Lr[0] + ((m & 1) ? -Lr[8] : Lr[8]);
#pragma unroll
                for (int f = 1; f < 8; f++)
                    s += 2.0f * (Lr[f] * ct[f][m] - Li[f] * st_[f][m]);
                ax[obase + (long)(16 * h + m) * 4096]        = s * 0.0625f;
                ax[obase + (long)(128 + 16 * h + m) * 4096]  = o1[m];
            }
        }
    }
}

// ---------------------------------------------------------------------------
// Host launch
// ---------------------------------------------------------------------------
extern "C" void kernel_launch(void* const* d_in, const int* in_sizes, int n_in,
                              void* d_out, int out_size, void* d_ws, size_t ws_size,
                              hipStream_t stream)
{
    const float* x          = (const float*)d_in[0];
    const float* pc3a_w     = (const float*)d_in[1];
    const float* hm_conv1_w = (const float*)d_in[2];
    const float* hm_proj2_w = (const float*)d_in[3];
    const float* hm_proj2_b = (const float*)d_in[4];
    const float* pc5_w      = (const float*)d_in[5];
    const float* hm_conv2_w = (const float*)d_in[6];
    const float* fuse_w     = (const float*)d_in[7];
    const float* qkv_pc3_w  = (const float*)d_in[8];
    const float* qkv_w      = (const float*)d_in[9];
    const float* proj_w     = (const float*)d_in[10];
    const float* proj_b     = (const float*)d_in[11];
    const float* temp1      = (const float*)d_in[12];
    const float* temp2      = (const float*)d_in[13];
    const float* tw1        = (const float*)d_in[14];
    const float* tw2        = (const float*)d_in[15];
    float* out = (float*)d_out;
    float* ws  = (float*)d_ws;

    // ws layout (floats): y[4.19M] | tmp[16.78M] | hx[16.78M] | qkv[25.17M]  = 240 MiB
    float* y   = ws;
    float* tmp = ws + 4194304L;
    float* hx  = ws + 20971520L;
    float* qkv = ws + 37748736L;
    float* ax  = tmp;  // tmp is dead once hx is complete

    const long bsx = 1048576L;  // 256*4096
    const long bsy = 262144L;   // 64*4096
    const long bsq = 1572864L;  // 384*4096

    dim3 cgrid(16, 4, 16);
    dim3 g256(64, 4, 16);
    dim3 g384(64, 6, 16);

    // branch 1: cx = gelu(W1 @ [conv3(x[:64]); x[64:]]);  hx = F1@cx + x
    conv_small<3><<<cgrid, 256, 0, stream>>>(x, bsx, pc3a_w, y);
    gemm1x1<<<g256, 256, 0, stream>>>(y, bsy, 64, x + 262144, bsx,
                                      hm_conv1_w, 256, 0, 0,
                                      nullptr, nullptr, 0, 0, 1, tmp, bsx, 256);
    gemm1x1<<<g256, 256, 0, stream>>>(tmp, bsx, 256, nullptr, 0,
                                      fuse_w, 768, 0, 0,
                                      nullptr, x, bsx, 0, 0, hx, bsx, 256);
    // branch 3: rx = gelu(W3 @ [conv5(x[:64]); x[64:]]);  hx += F3@rx
    conv_small<5><<<cgrid, 256, 0, stream>>>(x, bsx, pc5_w, y);
    gemm1x1<<<g256, 256, 0, stream>>>(y, bsy, 64, x + 262144, bsx,
                                      hm_conv2_w, 256, 0, 0,
                                      nullptr, nullptr, 0, 0, 1, tmp, bsx, 256);
    gemm1x1<<<g256, 256, 0, stream>>>(tmp, bsx, 256, nullptr, 0,
                                      fuse_w, 768, 512, 0,
                                      nullptr, nullptr, 0, 1, 0, hx, bsx, 256);
    // branch 2: px = gelu(W2 @ x + b2);  hx += F2@px
    gemm1x1<<<g256, 256, 0, stream>>>(x, bsx, 256, nullptr, 0,
                                      hm_proj2_w, 256, 0, 0,
                                      hm_proj2_b, nullptr, 0, 0, 1, tmp, bsx, 256);
    gemm1x1<<<g256, 256, 0, stream>>>(tmp, bsx, 256, nullptr, 0,
                                      fuse_w, 768, 256, 0,
                                      nullptr, nullptr, 0, 1, 0, hx, bsx, 256);
    // qkv = qkv_w' @ [conv3(hx[:64]); hx[64:]]  (only the 384 used rows)
    conv_small<3><<<cgrid, 256, 0, stream>>>(hx, bsx, qkv_pc3_w, y);
    gemm1x1<<<g384, 256, 0, stream>>>(y, bsy, 64, hx + 262144, bsx,
                                      qkv_w, 256, 0, 1,
                                      nullptr, nullptr, 0, 0, 0, qkv, bsq, 256);
    // dual attention (channel + spectral), writes ax = [lx ; out1]
    attn_kernel<<<128, 256, 0, stream>>>(qkv, temp1, temp2, tw1, tw2, ax);
    // out = proj_w @ ax + proj_b
    gemm1x1<<<g256, 256, 0, stream>>>(ax, bsx, 256, nullptr, 0,
                                      proj_w, 256, 0, 0,
                                      proj_b, nullptr, 0, 0, 0, out, bsx, 256);
}

// Round 2
// 2164.364 us; speedup vs baseline: 1.3509x; 1.3509x over previous
//
#include <hip/hip_runtime.h>
#include <math.h>

// ---------------------------------------------------------------------------
// Problem constants: B=16, DIM=256, H=W=64, HEADS=8, C2=16, CF=9, DC=64
// N_SP = H*W = 4096 tokens per batch, channel-major (NCHW) layout everywhere.
// ---------------------------------------------------------------------------

__device__ __forceinline__ float gelu_f(float v) {
    return 0.5f * v * (1.0f + erff(v * 0.70710678118654752440f));
}

// ---------------------------------------------------------------------------
// Generic 1x1-conv GEMM over tokens (unchanged from round 1 — passed).
// ---------------------------------------------------------------------------
__global__ __launch_bounds__(256) void gemm1x1(
    const float* __restrict__ in1, long bs1, int c1,
    const float* __restrict__ in2, long bs2,
    const float* __restrict__ W, int w_ld, int w_col_off, int rowmap,
    const float* __restrict__ bias, const float* __restrict__ addsrc, long bs_add,
    int accum, int do_gelu,
    float* __restrict__ out, long bs_out, int K)
{
    __shared__ float Wt[32][68];
    __shared__ float It[32][68];
    const int t  = threadIdx.x;
    const int b  = blockIdx.z;
    const int n0 = blockIdx.x * 64;
    const int o0 = blockIdx.y * 64;
    const int ty = t >> 4, tx = t & 15;

    float acc[4][4];
#pragma unroll
    for (int i = 0; i < 4; i++)
#pragma unroll
        for (int j = 0; j < 4; j++) acc[i][j] = 0.f;

    const float* i1b = in1 + (long)b * bs1;
    const float* i2b = in2 ? (in2 + (long)b * bs2) : nullptr;

    for (int kk = 0; kk < K; kk += 32) {
        __syncthreads();
#pragma unroll
        for (int i = 0; i < 8; i++) {
            int e  = i * 256 + t;
            int ol = e >> 5, kc = e & 31;
            int o  = o0 + ol;
            int row = o;
            if (rowmap) row = ((o >> 7) << 8) + (((o >> 4) & 7) << 5) + 16 + (o & 15);
            Wt[kc][ol] = W[(long)row * w_ld + w_col_off + kk + kc];
        }
#pragma unroll
        for (int i = 0; i < 8; i++) {
            int e  = i * 256 + t;
            int kr = e >> 6, nl = e & 63;
            int c  = kk + kr;
            const float* src = (c < c1) ? (i1b + (long)c * 4096)
                                        : (i2b + (long)(c - c1) * 4096);
            It[kr][nl] = src[n0 + nl];
        }
        __syncthreads();
#pragma unroll
        for (int k = 0; k < 32; k++) {
            float a4[4], b4[4];
            *(float4*)a4 = *(const float4*)&Wt[k][ty * 4];
            *(float4*)b4 = *(const float4*)&It[k][tx * 4];
#pragma unroll
            for (int i = 0; i < 4; i++)
#pragma unroll
                for (int j = 0; j < 4; j++) acc[i][j] += a4[i] * b4[j];
        }
    }

#pragma unroll
    for (int i = 0; i < 4; i++) {
        int o = o0 + ty * 4 + i;
        float bv = bias ? bias[o] : 0.f;
        float v0 = acc[i][0] + bv, v1 = acc[i][1] + bv, v2 = acc[i][2] + bv, v3 = acc[i][3] + bv;
        if (do_gelu) { v0 = gelu_f(v0); v1 = gelu_f(v1); v2 = gelu_f(v2); v3 = gelu_f(v3); }
        long idx = (long)b * bs_out + (long)o * 4096 + n0 + tx * 4;
        if (addsrc) {
            const float4 a = *(const float4*)&addsrc[(long)b * bs_add + (long)o * 4096 + n0 + tx * 4];
            v0 += a.x; v1 += a.y; v2 += a.z; v3 += a.w;
        }
        if (accum) {
            const float4 old = *(const float4*)&out[idx];
            v0 += old.x; v1 += old.y; v2 += old.z; v3 += old.w;
        }
        float4 r; r.x = v0; r.y = v1; r.z = v2; r.w = v3;
        *(float4*)&out[idx] = r;
    }
}

// ---------------------------------------------------------------------------
// Weight transpose: OIHW [oc][ic][ky][kx] -> [tap][ic][oc] (oc fastest).
// Makes the 16 oc-weights per (ic,tap) one contiguous 64B scalar load.
// ---------------------------------------------------------------------------
__global__ void transpose_w(const float* __restrict__ w, float* __restrict__ wT, int KK) {
    int idx = blockIdx.x * 256 + threadIdx.x;
    int total = 64 * 64 * KK;
    if (idx >= total) return;
    int oc  = idx & 63;
    int ic  = (idx >> 6) & 63;
    int tap = idx >> 12;
    wT[idx] = w[(oc * 64 + ic) * KK + tap];
}

// ---------------------------------------------------------------------------
// Direct KxK conv v2 (SAME, zero-pad), 64ch -> 64ch, weights pre-transposed
// to [tap][ic][oc]. Weight fetch is a single uniform s_load_dwordx16 per
// (ic,tap); FMAs consume SGPR weight x per-lane VGPR input.
// Grid: (16 spatial tiles of 16x16, 4 oc-groups of 16, B). 256 threads.
// ---------------------------------------------------------------------------
template<int K>
__global__ __launch_bounds__(256) void conv_small2(
    const float* __restrict__ in, long bs_in,
    const float* __restrict__ wT, float* __restrict__ out)
{
    constexpr int R  = K / 2;
    constexpr int TW = 16 + 2 * R;
    __shared__ float lds[32 * TW * TW];
    const int t    = threadIdx.x;
    const int tile = blockIdx.x, ocg = blockIdx.y, b = blockIdx.z;
    const int ty0  = (tile >> 2) << 4, tx0 = (tile & 3) << 4;
    const int ty   = t >> 4, tx = t & 15;

    float acc[16];
#pragma unroll
    for (int i = 0; i < 16; i++) acc[i] = 0.f;

    const float* inb = in + (long)b * bs_in;

    for (int ich = 0; ich < 2; ich++) {
        __syncthreads();
        for (int e = t; e < 32 * TW * TW; e += 256) {
            int icl = e / (TW * TW);
            int rem = e % (TW * TW);
            int yy  = rem / TW + ty0 - R;
            int xx  = rem % TW + tx0 - R;
            float v = 0.f;
            if (yy >= 0 && yy < 64 && xx >= 0 && xx < 64)
                v = inb[(long)(ich * 32 + icl) * 4096 + yy * 64 + xx];
            lds[e] = v;
        }
        __syncthreads();
#pragma unroll 1
        for (int icl = 0; icl < 32; icl++) {
            const int ic = ich * 32 + icl;
            const float* lp = &lds[icl * TW * TW + ty * TW + tx];
            const float* wb = wT + (long)ic * 64 + ocg * 16;
#pragma unroll
            for (int ky = 0; ky < K; ky++)
#pragma unroll
                for (int kx = 0; kx < K; kx++) {
                    float v = lp[ky * TW + kx];
                    const float* wp = wb + (long)(ky * K + kx) * 4096;
#pragma unroll
                    for (int oc = 0; oc < 16; oc++)
                        acc[oc] = fmaf(wp[oc], v, acc[oc]);
                }
        }
    }
    long ob = (long)b * 262144 + (long)(ocg * 16) * 4096 + (ty0 + ty) * 64 + (tx0 + tx);
#pragma unroll
    for (int oc = 0; oc < 16; oc++) out[ob + (long)oc * 4096] = acc[oc];
}

// ---------------------------------------------------------------------------
// Attention per (b,h) — unchanged from round 1 (passed).
// ---------------------------------------------------------------------------
#define NC 128
#define ST 132

__global__ __launch_bounds__(256) void attn_kernel(
    const float* __restrict__ qkv,
    const float* __restrict__ temp1, const float* __restrict__ temp2,
    const float* __restrict__ tw1, const float* __restrict__ tw2,
    float* __restrict__ ax)
{
    const int bh = blockIdx.x;
    const int b = bh >> 3, h = bh & 7;
    const int t = threadIdx.x;

    __shared__ float qch[16][ST], kch[16][ST];
    __shared__ float qfr[9][ST], qfi[9][ST], kfr[9][ST], kfi[9][ST];
    __shared__ float ct[9][16], st_[9][16];
    __shared__ float S1[16][16], Sfr[9][9], Sfi[9][9];
    __shared__ float qss[16], kss[16], qfss[9], kfss[9];
    __shared__ float attn1[16][16], ar2[9][9], ai2[9][9];

    if (t < 144) {
        int f = t / 16, c = t % 16;
        float ang = 6.283185307179586f * (float)(f * c) / 16.0f;
        ct[f][c] = cosf(ang);
        st_[f][c] = sinf(ang);
    }

    const float* qbase = qkv + (long)b * 1572864 + (long)(16 * h) * 4096;
    const float* kbase = qbase + 128 * 4096;
    const float* vbase = qbase + 256 * 4096;

    float s1 = 0.f, sfr = 0.f, sfi = 0.f;
    float qssp = 0.f, kssp = 0.f, qfssp = 0.f, kfssp = 0.f;
    const int c0 = t >> 4, d0 = t & 15;
    const int cf = t / 9, df = t % 9;
    const int rr = t >> 4, jj0 = t & 15;

    for (int n0 = 0; n0 < 4096; n0 += NC) {
        __syncthreads();
#pragma unroll
        for (int i = 0; i < 8; i++) {
            int e = i * 256 + t, row = e >> 7, nn = e & 127;
            qch[row][nn] = qbase[(long)row * 4096 + n0 + nn];
            kch[row][nn] = kbase[(long)row * 4096 + n0 + nn];
        }
        __syncthreads();
        {
            int col = t & 127;
            bool isq = t < 128;
            float vv[16];
#pragma unroll
            for (int c = 0; c < 16; c++) vv[c] = isq ? qch[c][col] : kch[c][col];
#pragma unroll
            for (int f = 0; f < 9; f++) {
                float ar = 0.f, ai = 0.f;
#pragma unroll
                for (int c = 0; c < 16; c++) { ar += vv[c] * ct[f][c]; ai -= vv[c] * st_[f][c]; }
                if (isq) { qfr[f][col] = ar; qfi[f][col] = ai; }
                else     { kfr[f][col] = ar; kfi[f][col] = ai; }
            }
        }
#pragma unroll 4
        for (int n = 0; n < NC; n++) s1 += qch[c0][n] * kch[d0][n];
        for (int n = jj0; n < NC; n += 16) {
            float a = qch[rr][n]; qssp += a * a;
            float bq = kch[rr][n]; kssp += bq * bq;
        }
        __syncthreads();
        if (t < 81) {
#pragma unroll 4
            for (int n = 0; n < NC; n++) {
                float qr = qfr[cf][n], qi = qfi[cf][n];
                float kr = kfr[df][n], ki = kfi[df][n];
                sfr += qr * kr - qi * ki;
                sfi += qr * ki + qi * kr;
            }
        }
        if (t < 144) {
            int f = t >> 4;
            for (int n = jj0; n < NC; n += 16) {
                qfssp += qfr[f][n] * qfr[f][n] + qfi[f][n] * qfi[f][n];
                kfssp += kfr[f][n] * kfr[f][n] + kfi[f][n] * kfi[f][n];
            }
        }
    }
    __syncthreads();
    S1[c0][d0] = s1;
    if (t < 81) { Sfr[cf][df] = sfr; Sfi[cf][df] = sfi; }
#pragma unroll
    for (int off = 8; off; off >>= 1) {
        qssp  += __shfl_xor(qssp, off);
        kssp  += __shfl_xor(kssp, off);
        qfssp += __shfl_xor(qfssp, off);
        kfssp += __shfl_xor(kfssp, off);
    }
    if (jj0 == 0) { qss[rr] = qssp; kss[rr] = kssp; }
    if (jj0 == 0 && t < 144) { qfss[rr] = qfssp; kfss[rr] = kfssp; }
    __syncthreads();

    const float t1s = temp1[h], t2s = temp2[h];
    if (t < 16) {
        int c = t;
        float nq = fmaxf(sqrtf(qss[c]), 1e-12f);
        float vals[16];
        float m = -1e30f;
#pragma unroll
        for (int d = 0; d < 16; d++) {
            float nk = fmaxf(sqrtf(kss[d]), 1e-12f);
            float v = S1[c][d] / (nq * nk) * t1s;
            vals[d] = v; m = fmaxf(m, v);
        }
        float s = 0.f;
#pragma unroll
        for (int d = 0; d < 16; d++) { vals[d] = expf(vals[d] - m); s += vals[d]; }
#pragma unroll
        for (int d = 0; d < 16; d++)
            attn1[c][d] = vals[d] / s * tw2[(h * 16 + c) * 16 + d];
    }
    if (t >= 32 && t < 41) {
        int c = t - 32;
        float nq = fmaxf(sqrtf(qfss[c]), 1e-12f);
        float vr[9], vi[9];
        float mr = -1e30f, mi = -1e30f;
#pragma unroll
        for (int d = 0; d < 9; d++) {
            float nk = fmaxf(sqrtf(kfss[d]), 1e-12f);
            float sc = t2s / (nq * nk);
            vr[d] = Sfr[c][d] * sc; vi[d] = Sfi[c][d] * sc;
            mr = fmaxf(mr, vr[d]); mi = fmaxf(mi, vi[d]);
        }
        float sr = 0.f, si = 0.f;
#pragma unroll
        for (int d = 0; d < 9; d++) {
            vr[d] = expf(vr[d] - mr); sr += vr[d];
            vi[d] = expf(vi[d] - mi); si += vi[d];
        }
#pragma unroll
        for (int d = 0; d < 9; d++) {
            float tw = tw1[(h * 9 + c) * 9 + d];
            ar2[c][d] = vr[d] / sr * tw;
            ai2[c][d] = vi[d] / si * tw;
        }
    }
    __syncthreads();

    for (int n0 = 0; n0 < 4096; n0 += NC) {
        __syncthreads();
#pragma unroll
        for (int i = 0; i < 8; i++) {
            int e = i * 256 + t, row = e >> 7, nn = e & 127;
            qch[row][nn] = vbase[(long)row * 4096 + n0 + nn];
        }
        __syncthreads();
        if (t < 128) {
            int col = t;
            float vv[16];
#pragma unroll
            for (int c = 0; c < 16; c++) vv[c] = qch[c][col];
            float o1[16];
#pragma unroll
            for (int m = 0; m < 16; m++) {
                float a = 0.f;
#pragma unroll
                for (int d = 0; d < 16; d++) a += attn1[m][d] * vv[d];
                o1[m] = a;
            }
            float vfr[9], vfi[9];
#pragma unroll
            for (int f = 0; f < 9; f++) {
                float ar = 0.f, ai = 0.f;
#pragma unroll
                for (int c = 0; c < 16; c++) { ar += vv[c] * ct[f][c]; ai -= vv[c] * st_[f][c]; }
                vfr[f] = ar; vfi[f] = ai;
            }
            float Lr[9], Li[9];
#pragma unroll
            for (int c = 0; c < 9; c++) {
                float lr = 0.f, li = 0.f;
#pragma unroll
                for (int d = 0; d < 9; d++) {
                    lr += ar2[c][d] * vfr[d] - ai2[c][d] * vfi[d];
                    li += ar2[c][d] * vfi[d] + ai2[c][d] * vfr[d];
                }
                Lr[c] = lr; Li[c] = li;
            }
            long obase = (long)b * 1048576 + n0 + col;
#pragma unroll
            for (int m = 0; m < 16; m++) {
                float s = Lr[0] + ((m & 1) ? -Lr[8] : Lr[8]);
#pragma unroll
                for (int f = 1; f < 8; f++)
                    s += 2.0f * (Lr[f] * ct[f][m] - Li[f] * st_[f][m]);
                ax[obase + (long)(16 * h + m) * 4096]        = s * 0.0625f;
                ax[obase + (long)(128 + 16 * h + m) * 4096]  = o1[m];
            }
        }
    }
}

// ---------------------------------------------------------------------------
// Host launch
// ---------------------------------------------------------------------------
extern "C" void kernel_launch(void* const* d_in, const int* in_sizes, int n_in,
                              void* d_out, int out_size, void* d_ws, size_t ws_size,
                              hipStream_t stream)
{
    const float* x          = (const float*)d_in[0];
    const float* pc3a_w     = (const float*)d_in[1];
    const float* hm_conv1_w = (const float*)d_in[2];
    const float* hm_proj2_w = (const float*)d_in[3];
    const float* hm_proj2_b = (const float*)d_in[4];
    const float* pc5_w      = (const float*)d_in[5];
    const float* hm_conv2_w = (const float*)d_in[6];
    const float* fuse_w     = (const float*)d_in[7];
    const float* qkv_pc3_w  = (const float*)d_in[8];
    const float* qkv_w      = (const float*)d_in[9];
    const float* proj_w     = (const float*)d_in[10];
    const float* proj_b     = (const float*)d_in[11];
    const float* temp1      = (const float*)d_in[12];
    const float* temp2      = (const float*)d_in[13];
    const float* tw1        = (const float*)d_in[14];
    const float* tw2        = (const float*)d_in[15];
    float* out = (float*)d_out;
    float* ws  = (float*)d_ws;

    // ws layout (floats): y[4.19M] | tmp[16.78M] | hx[16.78M] | qkv[25.17M]
    float* y   = ws;
    float* tmp = ws + 4194304L;
    float* hx  = ws + 20971520L;
    float* qkv = ws + 37748736L;
    float* ax  = tmp;  // tmp is dead once hx is complete

    // transposed conv weights live at the head of the (not-yet-written) qkv
    // region; they are fully consumed before the qkv GEMM overwrites it.
    float* wT3a = qkv;                 // 64*64*9  = 36864
    float* wT5  = qkv + 36864L;        // 64*64*25 = 102400
    float* wT3q = qkv + 139264L;       // 64*64*9  = 36864

    const long bsx = 1048576L;
    const long bsy = 262144L;
    const long bsq = 1572864L;

    dim3 cgrid(16, 4, 16);
    dim3 g256(64, 4, 16);
    dim3 g384(64, 6, 16);

    transpose_w<<<144, 256, 0, stream>>>(pc3a_w, wT3a, 9);
    transpose_w<<<400, 256, 0, stream>>>(pc5_w, wT5, 25);
    transpose_w<<<144, 256, 0, stream>>>(qkv_pc3_w, wT3q, 9);

    // branch 1: cx = gelu(W1 @ [conv3(x[:64]); x[64:]]);  hx = F1@cx + x
    conv_small2<3><<<cgrid, 256, 0, stream>>>(x, bsx, wT3a, y);
    gemm1x1<<<g256, 256, 0, stream>>>(y, bsy, 64, x + 262144, bsx,
                                      hm_conv1_w, 256, 0, 0,
                                      nullptr, nullptr, 0, 0, 1, tmp, bsx, 256);
    gemm1x1<<<g256, 256, 0, stream>>>(tmp, bsx, 256, nullptr, 0,
                                      fuse_w, 768, 0, 0,
                                      nullptr, x, bsx, 0, 0, hx, bsx, 256);
    // branch 3: rx = gelu(W3 @ [conv5(x[:64]); x[64:]]);  hx += F3@rx
    conv_small2<5><<<cgrid, 256, 0, stream>>>(x, bsx, wT5, y);
    gemm1x1<<<g256, 256, 0, stream>>>(y, bsy, 64, x + 262144, bsx,
                                      hm_conv2_w, 256, 0, 0,
                                      nullptr, nullptr, 0, 0, 1, tmp, bsx, 256);
    gemm1x1<<<g256, 256, 0, stream>>>(tmp, bsx, 256, nullptr, 0,
                                      fuse_w, 768, 512, 0,
                                      nullptr, nullptr, 0, 1, 0, hx, bsx, 256);
    // branch 2: px = gelu(W2 @ x + b2);  hx += F2@px
    gemm1x1<<<g256, 256, 0, stream>>>(x, bsx, 256, nullptr, 0,
                                      hm_proj2_w, 256, 0, 0,
                                      hm_proj2_b, nullptr, 0, 0, 1, tmp, bsx, 256);
    gemm1x1<<<g256, 256, 0, stream>>>(tmp, bsx, 256, nullptr, 0,
                                      fuse_w, 768, 256, 0,
                                      nullptr, nullptr, 0, 1, 0, hx, bsx, 256);
    // qkv = qkv_w' @ [conv3(hx[:64]); hx[64:]]  (only the 384 used rows)
    conv_small2<3><<<cgrid, 256, 0, stream>>>(hx, bsx, wT3q, y);
    gemm1x1<<<g384, 256, 0, stream>>>(y, bsy, 64, hx + 262144, bsx,
                                      qkv_w, 256, 0, 1,
                                      nullptr, nullptr, 0, 0, 0, qkv, bsq, 256);
    // dual attention (channel + spectral), writes ax = [lx ; out1]
    attn_kernel<<<128, 256, 0, stream>>>(qkv, temp1, temp2, tw1, tw2, ax);
    // out = proj_w @ ax + proj_b
    gemm1x1<<<g256, 256, 0, stream>>>(ax, bsx, 256, nullptr, 0,
                                      proj_w, 256, 0, 0,
                                      proj_b, nullptr, 0, 0, 0, out, bsx, 256);
}

// Round 3
// 1769.627 us; speedup vs baseline: 1.6522x; 1.2231x over previous
//
#include <hip/hip_runtime.h>
#include <math.h>

// ---------------------------------------------------------------------------
// Problem constants: B=16, DIM=256, H=W=64, HEADS=8, C2=16, CF=9, DC=64
// N_SP = H*W = 4096 tokens per batch, channel-major (NCHW) layout everywhere.
// ---------------------------------------------------------------------------

__device__ __forceinline__ float gelu_f(float v) {
    return 0.5f * v * (1.0f + erff(v * 0.70710678118654752440f));
}

// ---------------------------------------------------------------------------
// Generic 1x1-conv GEMM over tokens (unchanged — passed).
// ---------------------------------------------------------------------------
__global__ __launch_bounds__(256) void gemm1x1(
    const float* __restrict__ in1, long bs1, int c1,
    const float* __restrict__ in2, long bs2,
    const float* __restrict__ W, int w_ld, int w_col_off, int rowmap,
    const float* __restrict__ bias, const float* __restrict__ addsrc, long bs_add,
    int accum, int do_gelu,
    float* __restrict__ out, long bs_out, int K)
{
    __shared__ float Wt[32][68];
    __shared__ float It[32][68];
    const int t  = threadIdx.x;
    const int b  = blockIdx.z;
    const int n0 = blockIdx.x * 64;
    const int o0 = blockIdx.y * 64;
    const int ty = t >> 4, tx = t & 15;

    float acc[4][4];
#pragma unroll
    for (int i = 0; i < 4; i++)
#pragma unroll
        for (int j = 0; j < 4; j++) acc[i][j] = 0.f;

    const float* i1b = in1 + (long)b * bs1;
    const float* i2b = in2 ? (in2 + (long)b * bs2) : nullptr;

    for (int kk = 0; kk < K; kk += 32) {
        __syncthreads();
#pragma unroll
        for (int i = 0; i < 8; i++) {
            int e  = i * 256 + t;
            int ol = e >> 5, kc = e & 31;
            int o  = o0 + ol;
            int row = o;
            if (rowmap) row = ((o >> 7) << 8) + (((o >> 4) & 7) << 5) + 16 + (o & 15);
            Wt[kc][ol] = W[(long)row * w_ld + w_col_off + kk + kc];
        }
#pragma unroll
        for (int i = 0; i < 8; i++) {
            int e  = i * 256 + t;
            int kr = e >> 6, nl = e & 63;
            int c  = kk + kr;
            const float* src = (c < c1) ? (i1b + (long)c * 4096)
                                        : (i2b + (long)(c - c1) * 4096);
            It[kr][nl] = src[n0 + nl];
        }
        __syncthreads();
#pragma unroll
        for (int k = 0; k < 32; k++) {
            float a4[4], b4[4];
            *(float4*)a4 = *(const float4*)&Wt[k][ty * 4];
            *(float4*)b4 = *(const float4*)&It[k][tx * 4];
#pragma unroll
            for (int i = 0; i < 4; i++)
#pragma unroll
                for (int j = 0; j < 4; j++) acc[i][j] += a4[i] * b4[j];
        }
    }

#pragma unroll
    for (int i = 0; i < 4; i++) {
        int o = o0 + ty * 4 + i;
        float bv = bias ? bias[o] : 0.f;
        float v0 = acc[i][0] + bv, v1 = acc[i][1] + bv, v2 = acc[i][2] + bv, v3 = acc[i][3] + bv;
        if (do_gelu) { v0 = gelu_f(v0); v1 = gelu_f(v1); v2 = gelu_f(v2); v3 = gelu_f(v3); }
        long idx = (long)b * bs_out + (long)o * 4096 + n0 + tx * 4;
        if (addsrc) {
            const float4 a = *(const float4*)&addsrc[(long)b * bs_add + (long)o * 4096 + n0 + tx * 4];
            v0 += a.x; v1 += a.y; v2 += a.z; v3 += a.w;
        }
        if (accum) {
            const float4 old = *(const float4*)&out[idx];
            v0 += old.x; v1 += old.y; v2 += old.z; v3 += old.w;
        }
        float4 r; r.x = v0; r.y = v1; r.z = v2; r.w = v3;
        *(float4*)&out[idx] = r;
    }
}

// ---------------------------------------------------------------------------
// Weight transpose: OIHW [oc][ic][ky][kx] -> [tap][ic][oc] (oc fastest).
// ---------------------------------------------------------------------------
__global__ void transpose_w(const float* __restrict__ w, float* __restrict__ wT, int KK) {
    int idx = blockIdx.x * 256 + threadIdx.x;
    int total = 64 * 64 * KK;
    if (idx >= total) return;
    int oc  = idx & 63;
    int ic  = (idx >> 6) & 63;
    int tap = idx >> 12;
    wT[idx] = w[(oc * 64 + ic) * KK + tap];
}

// ---------------------------------------------------------------------------
// Direct KxK conv v2 (unchanged — passed).
// ---------------------------------------------------------------------------
template<int K>
__global__ __launch_bounds__(256) void conv_small2(
    const float* __restrict__ in, long bs_in,
    const float* __restrict__ wT, float* __restrict__ out)
{
    constexpr int R  = K / 2;
    constexpr int TW = 16 + 2 * R;
    __shared__ float lds[32 * TW * TW];
    const int t    = threadIdx.x;
    const int tile = blockIdx.x, ocg = blockIdx.y, b = blockIdx.z;
    const int ty0  = (tile >> 2) << 4, tx0 = (tile & 3) << 4;
    const int ty   = t >> 4, tx = t & 15;

    float acc[16];
#pragma unroll
    for (int i = 0; i < 16; i++) acc[i] = 0.f;

    const float* inb = in + (long)b * bs_in;

    for (int ich = 0; ich < 2; ich++) {
        __syncthreads();
        for (int e = t; e < 32 * TW * TW; e += 256) {
            int icl = e / (TW * TW);
            int rem = e % (TW * TW);
            int yy  = rem / TW + ty0 - R;
            int xx  = rem % TW + tx0 - R;
            float v = 0.f;
            if (yy >= 0 && yy < 64 && xx >= 0 && xx < 64)
                v = inb[(long)(ich * 32 + icl) * 4096 + yy * 64 + xx];
            lds[e] = v;
        }
        __syncthreads();
#pragma unroll 1
        for (int icl = 0; icl < 32; icl++) {
            const int ic = ich * 32 + icl;
            const float* lp = &lds[icl * TW * TW + ty * TW + tx];
            const float* wb = wT + (long)ic * 64 + ocg * 16;
#pragma unroll
            for (int ky = 0; ky < K; ky++)
#pragma unroll
                for (int kx = 0; kx < K; kx++) {
                    float v = lp[ky * TW + kx];
                    const float* wp = wb + (long)(ky * K + kx) * 4096;
#pragma unroll
                    for (int oc = 0; oc < 16; oc++)
                        acc[oc] = fmaf(wp[oc], v, acc[oc]);
                }
        }
    }
    long ob = (long)b * 262144 + (long)(ocg * 16) * 4096 + (ty0 + ty) * 64 + (tx0 + tx);
#pragma unroll
    for (int oc = 0; oc < 16; oc++) out[ob + (long)oc * 4096] = acc[oc];
}

// ---------------------------------------------------------------------------
// Attention, restructured for occupancy (was: 128 blocks, 5.8% occ, 570 us).
//   attn_reduce: (8 n-chunks x 128 bh) blocks; partial S1 / Sf / sum-squares
//                over 512 columns each -> part[bh][chunk][512].
//   attn_mats:   128 blocks; sum partials, softmax+twiddle -> amats[bh][448].
//   attn_apply:  (16 col-chunks x 128 bh) blocks; per-column out1 + irfft.
// ---------------------------------------------------------------------------
#define NC 128
#define ST 132

__global__ __launch_bounds__(256) void attn_reduce(
    const float* __restrict__ qkv, float* __restrict__ part)
{
    const int chunk = blockIdx.x, bh = blockIdx.y;
    const int b = bh >> 3, h = bh & 7;
    const int t = threadIdx.x;

    __shared__ float qch[16][ST], kch[16][ST];
    __shared__ float qfr[9][ST], qfi[9][ST], kfr[9][ST], kfi[9][ST];
    __shared__ float ct[9][16], st_[9][16];

    if (t < 144) {
        int f = t / 16, c = t % 16;
        float ang = 6.283185307179586f * (float)(f * c) / 16.0f;
        ct[f][c] = cosf(ang);
        st_[f][c] = sinf(ang);
    }

    const float* qbase = qkv + (long)b * 1572864 + (long)(16 * h) * 4096;
    const float* kbase = qbase + 128 * 4096;

    float s1 = 0.f, sfr = 0.f, sfi = 0.f;
    float qssp = 0.f, kssp = 0.f, qfssp = 0.f, kfssp = 0.f;
    const int c0 = t >> 4, d0 = t & 15;
    const int cf = t / 9, df = t % 9;
    const int rr = t >> 4, jj0 = t & 15;

    const int nlo = chunk * 512, nhi = nlo + 512;
    for (int n0 = nlo; n0 < nhi; n0 += NC) {
        __syncthreads();
#pragma unroll
        for (int i = 0; i < 8; i++) {
            int e = i * 256 + t, row = e >> 7, nn = e & 127;
            qch[row][nn] = qbase[(long)row * 4096 + n0 + nn];
            kch[row][nn] = kbase[(long)row * 4096 + n0 + nn];
        }
        __syncthreads();
        {
            int col = t & 127;
            bool isq = t < 128;
            float vv[16];
#pragma unroll
            for (int c = 0; c < 16; c++) vv[c] = isq ? qch[c][col] : kch[c][col];
#pragma unroll
            for (int f = 0; f < 9; f++) {
                float ar = 0.f, ai = 0.f;
#pragma unroll
                for (int c = 0; c < 16; c++) { ar += vv[c] * ct[f][c]; ai -= vv[c] * st_[f][c]; }
                if (isq) { qfr[f][col] = ar; qfi[f][col] = ai; }
                else     { kfr[f][col] = ar; kfi[f][col] = ai; }
            }
        }
#pragma unroll 4
        for (int n = 0; n < NC; n++) s1 += qch[c0][n] * kch[d0][n];
        for (int n = jj0; n < NC; n += 16) {
            float a = qch[rr][n]; qssp += a * a;
            float bq = kch[rr][n]; kssp += bq * bq;
        }
        __syncthreads();
        if (t < 81) {
#pragma unroll 4
            for (int n = 0; n < NC; n++) {
                float qr = qfr[cf][n], qi = qfi[cf][n];
                float kr = kfr[df][n], ki = kfi[df][n];
                sfr += qr * kr - qi * ki;
                sfi += qr * ki + qi * kr;
            }
        }
        if (t < 144) {
            int f = t >> 4;
            for (int n = jj0; n < NC; n += 16) {
                qfssp += qfr[f][n] * qfr[f][n] + qfi[f][n] * qfi[f][n];
                kfssp += kfr[f][n] * kfr[f][n] + kfi[f][n] * kfi[f][n];
            }
        }
    }

#pragma unroll
    for (int off = 8; off; off >>= 1) {
        qssp  += __shfl_xor(qssp, off);
        kssp  += __shfl_xor(kssp, off);
        qfssp += __shfl_xor(qfssp, off);
        kfssp += __shfl_xor(kfssp, off);
    }
    float* pb = part + (long)(bh * 8 + chunk) * 512;
    pb[t] = s1;
    if (t < 81) { pb[256 + t] = sfr; pb[337 + t] = sfi; }
    if (jj0 == 0) { pb[448 + rr] = qssp; pb[464 + rr] = kssp; }
    if (jj0 == 0 && t < 144) { pb[480 + rr] = qfssp; pb[489 + rr] = kfssp; }
}

__global__ __launch_bounds__(256) void attn_mats(
    const float* __restrict__ part,
    const float* __restrict__ temp1, const float* __restrict__ temp2,
    const float* __restrict__ tw1, const float* __restrict__ tw2,
    float* __restrict__ amats)
{
    const int bh = blockIdx.x;
    const int h = bh & 7;
    const int t = threadIdx.x;

    __shared__ float S1[256], Sfr[81], Sfi[81];
    __shared__ float qss[16], kss[16], qfss[9], kfss[9];

    float s1 = 0.f, sfr = 0.f, sfi = 0.f, a0 = 0.f, a1 = 0.f, a2 = 0.f, a3 = 0.f;
#pragma unroll
    for (int ch = 0; ch < 8; ch++) {
        const float* p = part + (long)(bh * 8 + ch) * 512;
        s1 += p[t];
        if (t < 81) { sfr += p[256 + t]; sfi += p[337 + t]; }
        if (t < 16) { a0 += p[448 + t]; a1 += p[464 + t]; }
        if (t < 9)  { a2 += p[480 + t]; a3 += p[489 + t]; }
    }
    S1[t] = s1;
    if (t < 81) { Sfr[t] = sfr; Sfi[t] = sfi; }
    if (t < 16) { qss[t] = a0; kss[t] = a1; }
    if (t < 9)  { qfss[t] = a2; kfss[t] = a3; }
    __syncthreads();

    const float t1s = temp1[h], t2s = temp2[h];
    float* am = amats + (long)bh * 448;
    if (t < 16) {
        int c = t;
        float nq = fmaxf(sqrtf(qss[c]), 1e-12f);
        float vals[16];
        float m = -1e30f;
#pragma unroll
        for (int d = 0; d < 16; d++) {
            float nk = fmaxf(sqrtf(kss[d]), 1e-12f);
            float v = S1[c * 16 + d] / (nq * nk) * t1s;
            vals[d] = v; m = fmaxf(m, v);
        }
        float s = 0.f;
#pragma unroll
        for (int d = 0; d < 16; d++) { vals[d] = expf(vals[d] - m); s += vals[d]; }
#pragma unroll
        for (int d = 0; d < 16; d++)
            am[c * 16 + d] = vals[d] / s * tw2[(h * 16 + c) * 16 + d];
    }
    if (t >= 32 && t < 41) {
        int c = t - 32;
        float nq = fmaxf(sqrtf(qfss[c]), 1e-12f);
        float vr[9], vi[9];
        float mr = -1e30f, mi = -1e30f;
#pragma unroll
        for (int d = 0; d < 9; d++) {
            float nk = fmaxf(sqrtf(kfss[d]), 1e-12f);
            float sc = t2s / (nq * nk);
            vr[d] = Sfr[c * 9 + d] * sc; vi[d] = Sfi[c * 9 + d] * sc;
            mr = fmaxf(mr, vr[d]); mi = fmaxf(mi, vi[d]);
        }
        float sr = 0.f, si = 0.f;
#pragma unroll
        for (int d = 0; d < 9; d++) {
            vr[d] = expf(vr[d] - mr); sr += vr[d];
            vi[d] = expf(vi[d] - mi); si += vi[d];
        }
#pragma unroll
        for (int d = 0; d < 9; d++) {
            float tw = tw1[(h * 9 + c) * 9 + d];
            am[256 + c * 9 + d] = vr[d] / sr * tw;
            am[337 + c * 9 + d] = vi[d] / si * tw;
        }
    }
}

__global__ __launch_bounds__(256) void attn_apply(
    const float* __restrict__ qkv, const float* __restrict__ amats,
    float* __restrict__ ax)
{
    const int chunk = blockIdx.x, bh = blockIdx.y;
    const int b = bh >> 3, h = bh & 7;
    const int t = threadIdx.x;

    __shared__ float attn1[16][16], ar2[9][9], ai2[9][9];
    __shared__ float ct[9][16], st_[9][16];

    const float* am = amats + (long)bh * 448;
    attn1[t >> 4][t & 15] = am[t];
    if (t < 81) { ar2[t / 9][t % 9] = am[256 + t]; ai2[t / 9][t % 9] = am[337 + t]; }
    if (t < 144) {
        int f = t / 16, c = t % 16;
        float ang = 6.283185307179586f * (float)(f * c) / 16.0f;
        ct[f][c] = cosf(ang);
        st_[f][c] = sinf(ang);
    }
    __syncthreads();

    const int col = chunk * 256 + t;
    const float* vbase = qkv + (long)b * 1572864 + (long)(256 + 16 * h) * 4096;

    float vv[16];
#pragma unroll
    for (int c = 0; c < 16; c++) vv[c] = vbase[(long)c * 4096 + col];

    float o1[16];
#pragma unroll
    for (int m = 0; m < 16; m++) {
        float a = 0.f;
#pragma unroll
        for (int d = 0; d < 16; d++) a += attn1[m][d] * vv[d];
        o1[m] = a;
    }
    float vfr[9], vfi[9];
#pragma unroll
    for (int f = 0; f < 9; f++) {
        float ar = 0.f, ai = 0.f;
#pragma unroll
        for (int c = 0; c < 16; c++) { ar += vv[c] * ct[f][c]; ai -= vv[c] * st_[f][c]; }
        vfr[f] = ar; vfi[f] = ai;
    }
    float Lr[9], Li[9];
#pragma unroll
    for (int c = 0; c < 9; c++) {
        float lr = 0.f, li = 0.f;
#pragma unroll
        for (int d = 0; d < 9; d++) {
            lr += ar2[c][d] * vfr[d] - ai2[c][d] * vfi[d];
            li += ar2[c][d] * vfi[d] + ai2[c][d] * vfr[d];
        }
        Lr[c] = lr; Li[c] = li;
    }
    long obase = (long)b * 1048576 + col;
#pragma unroll
    for (int m = 0; m < 16; m++) {
        float s = Lr[0] + ((m & 1) ? -Lr[8] : Lr[8]);
#pragma unroll
        for (int f = 1; f < 8; f++)
            s += 2.0f * (Lr[f] * ct[f][m] - Li[f] * st_[f][m]);
        ax[obase + (long)(16 * h + m) * 4096]       = s * 0.0625f;
        ax[obase + (long)(128 + 16 * h + m) * 4096] = o1[m];
    }
}

// ---------------------------------------------------------------------------
// Host launch
// ---------------------------------------------------------------------------
extern "C" void kernel_launch(void* const* d_in, const int* in_sizes, int n_in,
                              void* d_out, int out_size, void* d_ws, size_t ws_size,
                              hipStream_t stream)
{
    const float* x          = (const float*)d_in[0];
    const float* pc3a_w     = (const float*)d_in[1];
    const float* hm_conv1_w = (const float*)d_in[2];
    const float* hm_proj2_w = (const float*)d_in[3];
    const float* hm_proj2_b = (const float*)d_in[4];
    const float* pc5_w      = (const float*)d_in[5];
    const float* hm_conv2_w = (const float*)d_in[6];
    const float* fuse_w     = (const float*)d_in[7];
    const float* qkv_pc3_w  = (const float*)d_in[8];
    const float* qkv_w      = (const float*)d_in[9];
    const float* proj_w     = (const float*)d_in[10];
    const float* proj_b     = (const float*)d_in[11];
    const float* temp1      = (const float*)d_in[12];
    const float* temp2      = (const float*)d_in[13];
    const float* tw1        = (const float*)d_in[14];
    const float* tw2        = (const float*)d_in[15];
    float* out = (float*)d_out;
    float* ws  = (float*)d_ws;

    // ws layout (floats): y[4.19M] | tmp[16.78M] | hx[16.78M] | qkv[25.17M]
    float* y   = ws;
    float* tmp = ws + 4194304L;
    float* hx  = ws + 20971520L;
    float* qkv = ws + 37748736L;
    float* ax  = tmp;  // tmp is dead once hx is complete

    // transposed conv weights at head of not-yet-written qkv region
    float* wT3a = qkv;
    float* wT5  = qkv + 36864L;
    float* wT3q = qkv + 139264L;
    // attention scratch: y region is dead after the qkv GEMM consumes it
    float* part  = y;                  // 128*8*512 = 524288 floats
    float* amats = y + 1048576L;       // 128*448   = 57344 floats

    const long bsx = 1048576L;
    const long bsy = 262144L;
    const long bsq = 1572864L;

    dim3 cgrid(16, 4, 16);
    dim3 g256(64, 4, 16);
    dim3 g384(64, 6, 16);

    transpose_w<<<144, 256, 0, stream>>>(pc3a_w, wT3a, 9);
    transpose_w<<<400, 256, 0, stream>>>(pc5_w, wT5, 25);
    transpose_w<<<144, 256, 0, stream>>>(qkv_pc3_w, wT3q, 9);

    // branch 1: cx = gelu(W1 @ [conv3(x[:64]); x[64:]]);  hx = F1@cx + x
    conv_small2<3><<<cgrid, 256, 0, stream>>>(x, bsx, wT3a, y);
    gemm1x1<<<g256, 256, 0, stream>>>(y, bsy, 64, x + 262144, bsx,
                                      hm_conv1_w, 256, 0, 0,
                                      nullptr, nullptr, 0, 0, 1, tmp, bsx, 256);
    gemm1x1<<<g256, 256, 0, stream>>>(tmp, bsx, 256, nullptr, 0,
                                      fuse_w, 768, 0, 0,
                                      nullptr, x, bsx, 0, 0, hx, bsx, 256);
    // branch 3: rx = gelu(W3 @ [conv5(x[:64]); x[64:]]);  hx += F3@rx
    conv_small2<5><<<cgrid, 256, 0, stream>>>(x, bsx, wT5, y);
    gemm1x1<<<g256, 256, 0, stream>>>(y, bsy, 64, x + 262144, bsx,
                                      hm_conv2_w, 256, 0, 0,
                                      nullptr, nullptr, 0, 0, 1, tmp, bsx, 256);
    gemm1x1<<<g256, 256, 0, stream>>>(tmp, bsx, 256, nullptr, 0,
                                      fuse_w, 768, 512, 0,
                                      nullptr, nullptr, 0, 1, 0, hx, bsx, 256);
    // branch 2: px = gelu(W2 @ x + b2);  hx += F2@px
    gemm1x1<<<g256, 256, 0, stream>>>(x, bsx, 256, nullptr, 0,
                                      hm_proj2_w, 256, 0, 0,
                                      hm_proj2_b, nullptr, 0, 0, 1, tmp, bsx, 256);
    gemm1x1<<<g256, 256, 0, stream>>>(tmp, bsx, 256, nullptr, 0,
                                      fuse_w, 768, 256, 0,
                                      nullptr, nullptr, 0, 1, 0, hx, bsx, 256);
    // qkv = qkv_w' @ [conv3(hx[:64]); hx[64:]]  (only the 384 used rows)
    conv_small2<3><<<cgrid, 256, 0, stream>>>(hx, bsx, wT3q, y);
    gemm1x1<<<g384, 256, 0, stream>>>(y, bsy, 64, hx + 262144, bsx,
                                      qkv_w, 256, 0, 1,
                                      nullptr, nullptr, 0, 0, 0, qkv, bsq, 256);
    // attention: reduce -> mats -> apply (y region now dead, reused)
    attn_reduce<<<dim3(8, 128), 256, 0, stream>>>(qkv, part);
    attn_mats<<<128, 256, 0, stream>>>(part, temp1, temp2, tw1, tw2, amats);
    attn_apply<<<dim3(16, 128), 256, 0, stream>>>(qkv, amats, ax);
    // out = proj_w @ ax + proj_b
    gemm1x1<<<g256, 256, 0, stream>>>(ax, bsx, 256, nullptr, 0,
                                      proj_w, 256, 0, 0,
                                      proj_b, nullptr, 0, 0, 0, out, bsx, 256);
}

// Round 4
// 926.460 us; speedup vs baseline: 3.1559x; 1.9101x over previous
//
#include <hip/hip_runtime.h>
#include <math.h>

// ---------------------------------------------------------------------------
// Problem constants: B=16, DIM=256, H=W=64, HEADS=8, C2=16, CF=9, DC=64
// N_SP = H*W = 4096 tokens per batch.
// Activations for MFMA GEMMs are TOKEN-major bf16 [b][4096][C] (K-contiguous).
// Channel-major f32 kept for: conv inputs, attention qkv, hx, final out.
// ---------------------------------------------------------------------------

typedef __attribute__((ext_vector_type(8))) short bf16x8;
typedef __attribute__((ext_vector_type(4))) float f32x4;

__device__ __forceinline__ float gelu_f(float v) {
    return 0.5f * v * (1.0f + erff(v * 0.70710678118654752440f));
}
__device__ __forceinline__ unsigned short f2bf(float f) {
    unsigned u = __builtin_bit_cast(unsigned, f);
    u += 0x7fffu + ((u >> 16) & 1u);
    return (unsigned short)(u >> 16);
}
__device__ __forceinline__ void store8bf(unsigned short* p, const float* v) {
    unsigned short h[8];
#pragma unroll
    for (int i = 0; i < 8; i++) h[i] = f2bf(v[i]);
    uint4 o;
    o.x = h[0] | ((unsigned)h[1] << 16);
    o.y = h[2] | ((unsigned)h[3] << 16);
    o.z = h[4] | ((unsigned)h[5] << 16);
    o.w = h[6] | ((unsigned)h[7] << 16);
    *(uint4*)p = o;
}

// ---------------------------------------------------------------------------
// f32 -> bf16 flat convert (weights)
// ---------------------------------------------------------------------------
__global__ void cvt_bf16(const float* __restrict__ src, unsigned short* __restrict__ dst, int n) {
    int i = blockIdx.x * 256 + threadIdx.x;
    if (i < n) dst[i] = f2bf(src[i]);
}

// ---------------------------------------------------------------------------
// x [b][256][4096] f32 -> xT [b][4096][256] bf16 (LDS tile transpose)
// grid (64 n-tiles, 4 c-tiles, 16 b), 256 threads
// ---------------------------------------------------------------------------
__global__ __launch_bounds__(256) void cvt_xpose(
    const float* __restrict__ x, unsigned short* __restrict__ xT)
{
    __shared__ float tile[64][65];
    const int t = threadIdx.x;
    const int n0 = blockIdx.x * 64, c0 = blockIdx.y * 64, b = blockIdx.z;
    const float* xb = x + (long)b * 1048576;
#pragma unroll
    for (int i = 0; i < 16; i++) {
        int c = i * 4 + (t >> 6), n = t & 63;
        tile[c][n] = xb[(long)(c0 + c) * 4096 + n0 + n];
    }
    __syncthreads();
    unsigned short* xTb = xT + (long)b * 4096 * 256;
#pragma unroll
    for (int i = 0; i < 4; i++) {
        int n = i * 16 + (t >> 4), cc = (t & 15) * 4;
        unsigned short h0 = f2bf(tile[cc + 0][n]);
        unsigned short h1 = f2bf(tile[cc + 1][n]);
        unsigned short h2 = f2bf(tile[cc + 2][n]);
        unsigned short h3 = f2bf(tile[cc + 3][n]);
        uint2 val;
        val.x = h0 | ((unsigned)h1 << 16);
        val.y = h2 | ((unsigned)h3 << 16);
        *(uint2*)&xTb[(long)(n0 + n) * 256 + c0 + cc] = val;
    }
}

// ---------------------------------------------------------------------------
// MFMA bf16 GEMM: out[o][n] = sum_c W[row(o)][c] * in[c][n]  (per batch)
// in = token-major bf16: cols < c1 from in1T (ld 64), else in2T (ld ld2), abs col.
// Tile 128x128, 4 waves (2x2 of 64x64), BK=32, LDS pad to 40.
// mode 0: token-major bf16 out (gelu/bias opt, col_off), mode 1: ch-major f32,
// mode 2: both (f32 with addsrc residual).
// ---------------------------------------------------------------------------
#define LDP 40

__global__ __launch_bounds__(256) void mfma_gemm(
    const unsigned short* __restrict__ in1T, int c1,
    const unsigned short* __restrict__ in2T, int ld2,
    const unsigned short* __restrict__ Wb, int w_ld, int rowmap,
    const float* __restrict__ bias, const float* __restrict__ addsrc,
    int K, int mode, int do_gelu, int col_off,
    unsigned short* __restrict__ outT, int ldo,
    float* __restrict__ outF, long bsF)
{
    __shared__ unsigned short Asm[128 * LDP];
    __shared__ unsigned short Bsm[128 * LDP];
    const int t = threadIdx.x;
    const int b = blockIdx.z;
    const int n0 = blockIdx.x * 128, o0 = blockIdx.y * 128;
    const int w = t >> 6, l = t & 63;

    f32x4 acc[4][4];
#pragma unroll
    for (int m = 0; m < 4; m++)
#pragma unroll
        for (int n = 0; n < 4; n++) acc[m][n] = (f32x4){0.f, 0.f, 0.f, 0.f};

    const int srow = t >> 2;          // staging row 0..63
    const int scol = (t & 3) * 8;     // staging k-offset

    int oa0 = o0 + srow, oa1 = o0 + 64 + srow;
    int ra0 = oa0, ra1 = oa1;
    if (rowmap) {
        ra0 = ((oa0 >> 7) << 8) + (((oa0 >> 4) & 7) << 5) + 16 + (oa0 & 15);
        ra1 = ((oa1 >> 7) << 8) + (((oa1 >> 4) & 7) << 5) + 16 + (oa1 & 15);
    }
    const unsigned short* Ag0 = Wb + (long)ra0 * w_ld + scol;
    const unsigned short* Ag1 = Wb + (long)ra1 * w_ld + scol;
    const unsigned short* i1r0 = in1T ? in1T + ((long)b * 4096 + n0 + srow) * 64 + scol : (const unsigned short*)0;
    const unsigned short* i1r1 = in1T ? i1r0 + 64L * 64 : (const unsigned short*)0;
    const unsigned short* i2r0 = in2T + ((long)b * 4096 + n0 + srow) * (long)ld2 + scol;
    const unsigned short* i2r1 = i2r0 + 64L * ld2;

    const int wr = (w >> 1) * 64, wc = (w & 1) * 64;
    const int fr = l & 15, fq = l >> 4;

    for (int kk = 0; kk < K; kk += 32) {
        uint4 av0 = *(const uint4*)(Ag0 + kk);
        uint4 av1 = *(const uint4*)(Ag1 + kk);
        const unsigned short *pb0, *pb1;
        if (kk < c1) { pb0 = i1r0 + kk; pb1 = i1r1 + kk; }
        else         { pb0 = i2r0 + kk; pb1 = i2r1 + kk; }
        uint4 bv0 = *(const uint4*)pb0;
        uint4 bv1 = *(const uint4*)pb1;
        __syncthreads();
        *(uint4*)&Asm[srow * LDP + scol]        = av0;
        *(uint4*)&Asm[(64 + srow) * LDP + scol] = av1;
        *(uint4*)&Bsm[srow * LDP + scol]        = bv0;
        *(uint4*)&Bsm[(64 + srow) * LDP + scol] = bv1;
        __syncthreads();
        bf16x8 af[4], bf[4];
#pragma unroll
        for (int m = 0; m < 4; m++)
            af[m] = *(const bf16x8*)&Asm[(wr + m * 16 + fr) * LDP + fq * 8];
#pragma unroll
        for (int n = 0; n < 4; n++)
            bf[n] = *(const bf16x8*)&Bsm[(wc + n * 16 + fr) * LDP + fq * 8];
#pragma unroll
        for (int m = 0; m < 4; m++)
#pragma unroll
            for (int n = 0; n < 4; n++)
                acc[m][n] = __builtin_amdgcn_mfma_f32_16x16x32_bf16(af[m], bf[n], acc[m][n], 0, 0, 0);
    }

    // epilogue: D frag lane l: col n_sub = l&15, rows o_sub = (l>>4)*4 + reg
#pragma unroll
    for (int m = 0; m < 4; m++) {
        int ob = o0 + wr + m * 16 + fq * 4;
        float bv[4] = {0.f, 0.f, 0.f, 0.f};
        if (bias) {
#pragma unroll
            for (int r = 0; r < 4; r++) bv[r] = bias[ob + r];
        }
#pragma unroll
        for (int n = 0; n < 4; n++) {
            int ng = n0 + wc + n * 16 + fr;
            float e[4];
#pragma unroll
            for (int r = 0; r < 4; r++) {
                e[r] = acc[m][n][r] + bv[r];
                if (do_gelu) e[r] = gelu_f(e[r]);
            }
            if (addsrc) {
#pragma unroll
                for (int r = 0; r < 4; r++)
                    e[r] += addsrc[(long)b * bsF + (long)(ob + r) * 4096 + ng];
            }
            if (mode == 0 || mode == 2) {
                unsigned short h[4];
#pragma unroll
                for (int r = 0; r < 4; r++) h[r] = f2bf(e[r]);
                uint2 val;
                val.x = h[0] | ((unsigned)h[1] << 16);
                val.y = h[2] | ((unsigned)h[3] << 16);
                *(uint2*)&outT[((long)b * 4096 + ng) * (long)ldo + col_off + ob] = val;
            }
            if (mode == 1 || mode == 2) {
#pragma unroll
                for (int r = 0; r < 4; r++)
                    outF[(long)b * bsF + (long)(ob + r) * 4096 + ng] = e[r];
            }
        }
    }
}

// ---------------------------------------------------------------------------
// Conv weight transpose: OIHW [oc][ic][ky][kx] -> [tap][ic][oc] f32
// ---------------------------------------------------------------------------
__global__ void transpose_w(const float* __restrict__ w, float* __restrict__ wT, int KK) {
    int idx = blockIdx.x * 256 + threadIdx.x;
    int total = 64 * 64 * KK;
    if (idx >= total) return;
    int oc  = idx & 63;
    int ic  = (idx >> 6) & 63;
    int tap = idx >> 12;
    wT[idx] = w[(oc * 64 + ic) * KK + tap];
}

// ---------------------------------------------------------------------------
// Direct KxK conv (f32 in, ch-major) -> TOKEN-major bf16 out yT[b][4096][64].
// ---------------------------------------------------------------------------
template<int K>
__global__ __launch_bounds__(256) void conv_small2(
    const float* __restrict__ in, long bs_in,
    const float* __restrict__ wT, unsigned short* __restrict__ outT)
{
    constexpr int R  = K / 2;
    constexpr int TW = 16 + 2 * R;
    __shared__ float lds[32 * TW * TW];
    const int t    = threadIdx.x;
    const int tile = blockIdx.x, ocg = blockIdx.y, b = blockIdx.z;
    const int ty0  = (tile >> 2) << 4, tx0 = (tile & 3) << 4;
    const int ty   = t >> 4, tx = t & 15;

    float acc[16];
#pragma unroll
    for (int i = 0; i < 16; i++) acc[i] = 0.f;

    const float* inb = in + (long)b * bs_in;

    for (int ich = 0; ich < 2; ich++) {
        __syncthreads();
        for (int e = t; e < 32 * TW * TW; e += 256) {
            int icl = e / (TW * TW);
            int rem = e % (TW * TW);
            int yy  = rem / TW + ty0 - R;
            int xx  = rem % TW + tx0 - R;
            float v = 0.f;
            if (yy >= 0 && yy < 64 && xx >= 0 && xx < 64)
                v = inb[(long)(ich * 32 + icl) * 4096 + yy * 64 + xx];
            lds[e] = v;
        }
        __syncthreads();
#pragma unroll 1
        for (int icl = 0; icl < 32; icl++) {
            const int ic = ich * 32 + icl;
            const float* lp = &lds[icl * TW * TW + ty * TW + tx];
            const float* wb = wT + (long)ic * 64 + ocg * 16;
#pragma unroll
            for (int ky = 0; ky < K; ky++)
#pragma unroll
                for (int kx = 0; kx < K; kx++) {
                    float v = lp[ky * TW + kx];
                    const float* wp = wb + (long)(ky * K + kx) * 4096;
#pragma unroll
                    for (int oc = 0; oc < 16; oc++)
                        acc[oc] = fmaf(wp[oc], v, acc[oc]);
                }
        }
    }
    int pix = (ty0 + ty) * 64 + tx0 + tx;
    unsigned short* op = outT + ((long)b * 4096 + pix) * 64 + ocg * 16;
    store8bf(op, acc);
    store8bf(op + 8, acc + 8);
}

// ---------------------------------------------------------------------------
// Attention (f32, unchanged math): reduce -> mats -> apply.
// attn_apply now writes TOKEN-major bf16 axT[b][4096][256].
// ---------------------------------------------------------------------------
#define NC 128
#define ST 132

__global__ __launch_bounds__(256) void attn_reduce(
    const float* __restrict__ qkv, float* __restrict__ part)
{
    const int chunk = blockIdx.x, bh = blockIdx.y;
    const int b = bh >> 3, h = bh & 7;
    const int t = threadIdx.x;

    __shared__ float qch[16][ST], kch[16][ST];
    __shared__ float qfr[9][ST], qfi[9][ST], kfr[9][ST], kfi[9][ST];
    __shared__ float ct[9][16], st_[9][16];

    if (t < 144) {
        int f = t / 16, c = t % 16;
        float ang = 6.283185307179586f * (float)(f * c) / 16.0f;
        ct[f][c] = cosf(ang);
        st_[f][c] = sinf(ang);
    }

    const float* qbase = qkv + (long)b * 1572864 + (long)(16 * h) * 4096;
    const float* kbase = qbase + 128 * 4096;

    float s1 = 0.f, sfr = 0.f, sfi = 0.f;
    float qssp = 0.f, kssp = 0.f, qfssp = 0.f, kfssp = 0.f;
    const int c0 = t >> 4, d0 = t & 15;
    const int cf = t / 9, df = t % 9;
    const int rr = t >> 4, jj0 = t & 15;

    const int nlo = chunk * 512, nhi = nlo + 512;
    for (int n0 = nlo; n0 < nhi; n0 += NC) {
        __syncthreads();
#pragma unroll
        for (int i = 0; i < 8; i++) {
            int e = i * 256 + t, row = e >> 7, nn = e & 127;
            qch[row][nn] = qbase[(long)row * 4096 + n0 + nn];
            kch[row][nn] = kbase[(long)row * 4096 + n0 + nn];
        }
        __syncthreads();
        {
            int col = t & 127;
            bool isq = t < 128;
            float vv[16];
#pragma unroll
            for (int c = 0; c < 16; c++) vv[c] = isq ? qch[c][col] : kch[c][col];
#pragma unroll
            for (int f = 0; f < 9; f++) {
                float ar = 0.f, ai = 0.f;
#pragma unroll
                for (int c = 0; c < 16; c++) { ar += vv[c] * ct[f][c]; ai -= vv[c] * st_[f][c]; }
                if (isq) { qfr[f][col] = ar; qfi[f][col] = ai; }
                else     { kfr[f][col] = ar; kfi[f][col] = ai; }
            }
        }
#pragma unroll 4
        for (int n = 0; n < NC; n++) s1 += qch[c0][n] * kch[d0][n];
        for (int n = jj0; n < NC; n += 16) {
            float a = qch[rr][n]; qssp += a * a;
            float bq = kch[rr][n]; kssp += bq * bq;
        }
        __syncthreads();
        if (t < 81) {
#pragma unroll 4
            for (int n = 0; n < NC; n++) {
                float qr = qfr[cf][n], qi = qfi[cf][n];
                float kr = kfr[df][n], ki = kfi[df][n];
                sfr += qr * kr - qi * ki;
                sfi += qr * ki + qi * kr;
            }
        }
        if (t < 144) {
            int f = t >> 4;
            for (int n = jj0; n < NC; n += 16) {
                qfssp += qfr[f][n] * qfr[f][n] + qfi[f][n] * qfi[f][n];
                kfssp += kfr[f][n] * kfr[f][n] + kfi[f][n] * kfi[f][n];
            }
        }
    }

#pragma unroll
    for (int off = 8; off; off >>= 1) {
        qssp  += __shfl_xor(qssp, off);
        kssp  += __shfl_xor(kssp, off);
        qfssp += __shfl_xor(qfssp, off);
        kfssp += __shfl_xor(kfssp, off);
    }
    float* pb = part + (long)(bh * 8 + chunk) * 512;
    pb[t] = s1;
    if (t < 81) { pb[256 + t] = sfr; pb[337 + t] = sfi; }
    if (jj0 == 0) { pb[448 + rr] = qssp; pb[464 + rr] = kssp; }
    if (jj0 == 0 && t < 144) { pb[480 + rr] = qfssp; pb[489 + rr] = kfssp; }
}

__global__ __launch_bounds__(256) void attn_mats(
    const float* __restrict__ part,
    const float* __restrict__ temp1, const float* __restrict__ temp2,
    const float* __restrict__ tw1, const float* __restrict__ tw2,
    float* __restrict__ amats)
{
    const int bh = blockIdx.x;
    const int h = bh & 7;
    const int t = threadIdx.x;

    __shared__ float S1[256], Sfr[81], Sfi[81];
    __shared__ float qss[16], kss[16], qfss[9], kfss[9];

    float s1 = 0.f, sfr = 0.f, sfi = 0.f, a0 = 0.f, a1 = 0.f, a2 = 0.f, a3 = 0.f;
#pragma unroll
    for (int ch = 0; ch < 8; ch++) {
        const float* p = part + (long)(bh * 8 + ch) * 512;
        s1 += p[t];
        if (t < 81) { sfr += p[256 + t]; sfi += p[337 + t]; }
        if (t < 16) { a0 += p[448 + t]; a1 += p[464 + t]; }
        if (t < 9)  { a2 += p[480 + t]; a3 += p[489 + t]; }
    }
    S1[t] = s1;
    if (t < 81) { Sfr[t] = sfr; Sfi[t] = sfi; }
    if (t < 16) { qss[t] = a0; kss[t] = a1; }
    if (t < 9)  { qfss[t] = a2; kfss[t] = a3; }
    __syncthreads();

    const float t1s = temp1[h], t2s = temp2[h];
    float* am = amats + (long)bh * 448;
    if (t < 16) {
        int c = t;
        float nq = fmaxf(sqrtf(qss[c]), 1e-12f);
        float vals[16];
        float m = -1e30f;
#pragma unroll
        for (int d = 0; d < 16; d++) {
            float nk = fmaxf(sqrtf(kss[d]), 1e-12f);
            float v = S1[c * 16 + d] / (nq * nk) * t1s;
            vals[d] = v; m = fmaxf(m, v);
        }
        float s = 0.f;
#pragma unroll
        for (int d = 0; d < 16; d++) { vals[d] = expf(vals[d] - m); s += vals[d]; }
#pragma unroll
        for (int d = 0; d < 16; d++)
            am[c * 16 + d] = vals[d] / s * tw2[(h * 16 + c) * 16 + d];
    }
    if (t >= 32 && t < 41) {
        int c = t - 32;
        float nq = fmaxf(sqrtf(qfss[c]), 1e-12f);
        float vr[9], vi[9];
        float mr = -1e30f, mi = -1e30f;
#pragma unroll
        for (int d = 0; d < 9; d++) {
            float nk = fmaxf(sqrtf(kfss[d]), 1e-12f);
            float sc = t2s / (nq * nk);
            vr[d] = Sfr[c * 9 + d] * sc; vi[d] = Sfi[c * 9 + d] * sc;
            mr = fmaxf(mr, vr[d]); mi = fmaxf(mi, vi[d]);
        }
        float sr = 0.f, si = 0.f;
#pragma unroll
        for (int d = 0; d < 9; d++) {
            vr[d] = expf(vr[d] - mr); sr += vr[d];
            vi[d] = expf(vi[d] - mi); si += vi[d];
        }
#pragma unroll
        for (int d = 0; d < 9; d++) {
            float tw = tw1[(h * 9 + c) * 9 + d];
            am[256 + c * 9 + d] = vr[d] / sr * tw;
            am[337 + c * 9 + d] = vi[d] / si * tw;
        }
    }
}

__global__ __launch_bounds__(256) void attn_apply(
    const float* __restrict__ qkv, const float* __restrict__ amats,
    unsigned short* __restrict__ axT)
{
    const int chunk = blockIdx.x, bh = blockIdx.y;
    const int b = bh >> 3, h = bh & 7;
    const int t = threadIdx.x;

    __shared__ float attn1[16][16], ar2[9][9], ai2[9][9];
    __shared__ float ct[9][16], st_[9][16];

    const float* am = amats + (long)bh * 448;
    attn1[t >> 4][t & 15] = am[t];
    if (t < 81) { ar2[t / 9][t % 9] = am[256 + t]; ai2[t / 9][t % 9] = am[337 + t]; }
    if (t < 144) {
        int f = t / 16, c = t % 16;
        float ang = 6.283185307179586f * (float)(f * c) / 16.0f;
        ct[f][c] = cosf(ang);
        st_[f][c] = sinf(ang);
    }
    __syncthreads();

    const int col = chunk * 256 + t;
    const float* vbase = qkv + (long)b * 1572864 + (long)(256 + 16 * h) * 4096;

    float vv[16];
#pragma unroll
    for (int c = 0; c < 16; c++) vv[c] = vbase[(long)c * 4096 + col];

    float o1[16];
#pragma unroll
    for (int m = 0; m < 16; m++) {
        float a = 0.f;
#pragma unroll
        for (int d = 0; d < 16; d++) a += attn1[m][d] * vv[d];
        o1[m] = a;
    }
    float vfr[9], vfi[9];
#pragma unroll
    for (int f = 0; f < 9; f++) {
        float ar = 0.f, ai = 0.f;
#pragma unroll
        for (int c = 0; c < 16; c++) { ar += vv[c] * ct[f][c]; ai -= vv[c] * st_[f][c]; }
        vfr[f] = ar; vfi[f] = ai;
    }
    float Lr[9], Li[9];
#pragma unroll
    for (int c = 0; c < 9; c++) {
        float lr = 0.f, li = 0.f;
#pragma unroll
        for (int d = 0; d < 9; d++) {
            lr += ar2[c][d] * vfr[d] - ai2[c][d] * vfi[d];
            li += ar2[c][d] * vfi[d] + ai2[c][d] * vfr[d];
        }
        Lr[c] = lr; Li[c] = li;
    }
    float lx[16];
#pragma unroll
    for (int m = 0; m < 16; m++) {
        float s = Lr[0] + ((m & 1) ? -Lr[8] : Lr[8]);
#pragma unroll
        for (int f = 1; f < 8; f++)
            s += 2.0f * (Lr[f] * ct[f][m] - Li[f] * st_[f][m]);
        lx[m] = s * 0.0625f;
    }
    unsigned short* op = axT + ((long)b * 4096 + col) * 256;
    store8bf(op + 16 * h,       lx);
    store8bf(op + 16 * h + 8,   lx + 8);
    store8bf(op + 128 + 16 * h,     o1);
    store8bf(op + 128 + 16 * h + 8, o1 + 8);
}

// ---------------------------------------------------------------------------
// Host launch
// ---------------------------------------------------------------------------
extern "C" void kernel_launch(void* const* d_in, const int* in_sizes, int n_in,
                              void* d_out, int out_size, void* d_ws, size_t ws_size,
                              hipStream_t stream)
{
    const float* x          = (const float*)d_in[0];
    const float* pc3a_w     = (const float*)d_in[1];
    const float* hm_conv1_w = (const float*)d_in[2];
    const float* hm_proj2_w = (const float*)d_in[3];
    const float* hm_proj2_b = (const float*)d_in[4];
    const float* pc5_w      = (const float*)d_in[5];
    const float* hm_conv2_w = (const float*)d_in[6];
    const float* fuse_w     = (const float*)d_in[7];
    const float* qkv_pc3_w  = (const float*)d_in[8];
    const float* qkv_w      = (const float*)d_in[9];
    const float* proj_w     = (const float*)d_in[10];
    const float* proj_b     = (const float*)d_in[11];
    const float* temp1      = (const float*)d_in[12];
    const float* temp2      = (const float*)d_in[13];
    const float* tw1        = (const float*)d_in[14];
    const float* tw2        = (const float*)d_in[15];
    float* out = (float*)d_out;
    char* wsb  = (char*)d_ws;

    // ---- workspace layout (bytes) ----
    float*          hx    = (float*)(wsb + 0);                 //  67,108,864
    unsigned short* catT  = (unsigned short*)(wsb + 67108864); // 100,663,296 (union with qkv)
    float*          qkv   = (float*)(wsb + 67108864);
    unsigned short* xT    = (unsigned short*)(wsb + 167772160);//  33,554,432 (union with axT)
    unsigned short* axT   = (unsigned short*)(wsb + 167772160);
    unsigned short* hxT   = (unsigned short*)(wsb + 201326592);//  33,554,432
    unsigned short* yT    = (unsigned short*)(wsb + 234881024);//   8,388,608
    float*          part  = (float*)(wsb + 234881024);         // alias yT (after qkv GEMM)
    float*          amats = (float*)(wsb + 234881024 + 2097152);
    unsigned short* w1b   = (unsigned short*)(wsb + 243269632);// hm_conv1  65536
    unsigned short* w2b   = (unsigned short*)(wsb + 243400704);// hm_proj2  65536
    unsigned short* w3b   = (unsigned short*)(wsb + 243531776);// hm_conv2  65536
    unsigned short* wfb   = (unsigned short*)(wsb + 243662848);// fuse     196608
    unsigned short* wqb   = (unsigned short*)(wsb + 244056064);// qkv      196608
    unsigned short* wpb   = (unsigned short*)(wsb + 244449280);// proj      65536
    float*          wT3a  = (float*)(wsb + 244580352);
    float*          wT5   = (float*)(wsb + 244727808);
    float*          wT3q  = (float*)(wsb + 245137408);

    const long bsx = 1048576L;   // 256*4096 floats

    dim3 cgrid(16, 4, 16);
    dim3 gg2(32, 2, 16);  // M=256 GEMMs
    dim3 gg3(32, 3, 16);  // M=384 (qkv)

    // ---- prep: weight conversions / transposes ----
    cvt_bf16<<<256, 256, 0, stream>>>(hm_conv1_w, w1b, 65536);
    cvt_bf16<<<256, 256, 0, stream>>>(hm_proj2_w, w2b, 65536);
    cvt_bf16<<<256, 256, 0, stream>>>(hm_conv2_w, w3b, 65536);
    cvt_bf16<<<768, 256, 0, stream>>>(fuse_w, wfb, 196608);
    cvt_bf16<<<768, 256, 0, stream>>>(qkv_w, wqb, 196608);
    cvt_bf16<<<256, 256, 0, stream>>>(proj_w, wpb, 65536);
    transpose_w<<<144, 256, 0, stream>>>(pc3a_w, wT3a, 9);
    transpose_w<<<400, 256, 0, stream>>>(pc5_w, wT5, 25);
    transpose_w<<<144, 256, 0, stream>>>(qkv_pc3_w, wT3q, 9);
    cvt_xpose<<<dim3(64, 4, 16), 256, 0, stream>>>(x, xT);

    // ---- branch 1: cx = gelu(W1 @ [conv3(x[:64]); x[64:]]) -> catT[:,0:256]
    conv_small2<3><<<cgrid, 256, 0, stream>>>(x, bsx, wT3a, yT);
    mfma_gemm<<<gg2, 256, 0, stream>>>(yT, 64, xT, 256, w1b, 256, 0,
                                       nullptr, nullptr, 256, 0, 1, 0,
                                       catT, 768, nullptr, 0);
    // ---- branch 3: rx = gelu(W3 @ [conv5(x[:64]); x[64:]]) -> catT[:,512:768]
    conv_small2<5><<<cgrid, 256, 0, stream>>>(x, bsx, wT5, yT);
    mfma_gemm<<<gg2, 256, 0, stream>>>(yT, 64, xT, 256, w3b, 256, 0,
                                       nullptr, nullptr, 256, 0, 1, 512,
                                       catT, 768, nullptr, 0);
    // ---- branch 2: px = gelu(W2 @ x + b2) -> catT[:,256:512]
    mfma_gemm<<<gg2, 256, 0, stream>>>(nullptr, 0, xT, 256, w2b, 256, 0,
                                       hm_proj2_b, nullptr, 256, 0, 1, 256,
                                       catT, 768, nullptr, 0);
    // ---- fuse: hx = fuse_w @ catT + x  (f32 ch-major + bf16 token-major)
    mfma_gemm<<<gg2, 256, 0, stream>>>(nullptr, 0, catT, 768, wfb, 768, 0,
                                       nullptr, x, 768, 2, 0, 0,
                                       hxT, 256, hx, bsx);
    // ---- qkv = qkv_w'[384 rows] @ [conv3(hx[:64]); hx[64:]]  (f32 ch-major)
    conv_small2<3><<<cgrid, 256, 0, stream>>>(hx, bsx, wT3q, yT);
    mfma_gemm<<<gg3, 256, 0, stream>>>(yT, 64, hxT, 256, wqb, 256, 1,
                                       nullptr, nullptr, 256, 1, 0, 0,
                                       nullptr, 0, qkv, 1572864L);
    // ---- attention: reduce -> mats -> apply (axT bf16 token-major)
    attn_reduce<<<dim3(8, 128), 256, 0, stream>>>(qkv, part);
    attn_mats<<<128, 256, 0, stream>>>(part, temp1, temp2, tw1, tw2, amats);
    attn_apply<<<dim3(16, 128), 256, 0, stream>>>(qkv, amats, axT);
    // ---- out = proj_w @ axT + proj_b  (f32 ch-major)
    mfma_gemm<<<gg2, 256, 0, stream>>>(nullptr, 0, axT, 256, wpb, 256, 0,
                                       proj_b, nullptr, 256, 1, 0, 0,
                                       nullptr, 0, out, bsx);
}

// Round 5
// 442.763 us; speedup vs baseline: 6.6036x; 2.0925x over previous
//
#include <hip/hip_runtime.h>
#include <math.h>

// ---------------------------------------------------------------------------
// Problem constants: B=16, DIM=256, H=W=64, HEADS=8, C2=16, CF=9, DC=64
// Activations for MFMA are TOKEN-major bf16 [b][4096][C] (K-contiguous).
// f32 kept only for: x (input, residual add), qkv (attention), final out.
// ---------------------------------------------------------------------------

typedef __attribute__((ext_vector_type(8))) short bf16x8;
typedef __attribute__((ext_vector_type(4))) float f32x4;

__device__ __forceinline__ float gelu_f(float v) {
    return 0.5f * v * (1.0f + erff(v * 0.70710678118654752440f));
}
__device__ __forceinline__ unsigned short f2bf(float f) {
    unsigned u = __builtin_bit_cast(unsigned, f);
    u += 0x7fffu + ((u >> 16) & 1u);
    return (unsigned short)(u >> 16);
}
__device__ __forceinline__ void store8bf(unsigned short* p, const float* v) {
    unsigned short h[8];
#pragma unroll
    for (int i = 0; i < 8; i++) h[i] = f2bf(v[i]);
    uint4 o;
    o.x = h[0] | ((unsigned)h[1] << 16);
    o.y = h[2] | ((unsigned)h[3] << 16);
    o.z = h[4] | ((unsigned)h[5] << 16);
    o.w = h[6] | ((unsigned)h[7] << 16);
    *(uint4*)p = o;
}

// ---------------------------------------------------------------------------
// f32 -> bf16 flat convert (weights)
// ---------------------------------------------------------------------------
__global__ void cvt_bf16(const float* __restrict__ src, unsigned short* __restrict__ dst, int n) {
    int i = blockIdx.x * 256 + threadIdx.x;
    if (i < n) dst[i] = f2bf(src[i]);
}

// ---------------------------------------------------------------------------
// Conv weights OIHW f32 [oc][ic][tap] -> bf16 [tap][oc][ic]
// ---------------------------------------------------------------------------
__global__ void cvt_wconv(const float* __restrict__ w, unsigned short* __restrict__ wb, int KK) {
    int idx = blockIdx.x * 256 + threadIdx.x;
    if (idx >= 64 * 64 * KK) return;
    int ic = idx & 63, oc = (idx >> 6) & 63, tap = idx >> 12;
    wb[tap * 4096 + oc * 64 + ic] = f2bf(w[(oc * 64 + ic) * KK + tap]);
}

// ---------------------------------------------------------------------------
// x [b][256][4096] f32 -> xT [b][4096][256] bf16 (LDS tile transpose)
// ---------------------------------------------------------------------------
__global__ __launch_bounds__(256) void cvt_xpose(
    const float* __restrict__ x, unsigned short* __restrict__ xT)
{
    __shared__ float tile[64][65];
    const int t = threadIdx.x;
    const int n0 = blockIdx.x * 64, c0 = blockIdx.y * 64, b = blockIdx.z;
    const float* xb = x + (long)b * 1048576;
#pragma unroll
    for (int i = 0; i < 16; i++) {
        int c = i * 4 + (t >> 6), n = t & 63;
        tile[c][n] = xb[(long)(c0 + c) * 4096 + n0 + n];
    }
    __syncthreads();
    unsigned short* xTb = xT + (long)b * 4096 * 256;
#pragma unroll
    for (int i = 0; i < 4; i++) {
        int n = i * 16 + (t >> 4), cc = (t & 15) * 4;
        unsigned short h0 = f2bf(tile[cc + 0][n]);
        unsigned short h1 = f2bf(tile[cc + 1][n]);
        unsigned short h2 = f2bf(tile[cc + 2][n]);
        unsigned short h3 = f2bf(tile[cc + 3][n]);
        uint2 val;
        val.x = h0 | ((unsigned)h1 << 16);
        val.y = h2 | ((unsigned)h3 << 16);
        *(uint2*)&xTb[(long)(n0 + n) * 256 + c0 + cc] = val;
    }
}

// ---------------------------------------------------------------------------
// MFMA bf16 GEMM (unchanged from round 4 — passed).
// ---------------------------------------------------------------------------
#define LDP 40

__global__ __launch_bounds__(256) void mfma_gemm(
    const unsigned short* __restrict__ in1T, int c1,
    const unsigned short* __restrict__ in2T, int ld2,
    const unsigned short* __restrict__ Wb, int w_ld, int rowmap,
    const float* __restrict__ bias, const float* __restrict__ addsrc,
    int K, int mode, int do_gelu, int col_off,
    unsigned short* __restrict__ outT, int ldo,
    float* __restrict__ outF, long bsF)
{
    __shared__ unsigned short Asm[128 * LDP];
    __shared__ unsigned short Bsm[128 * LDP];
    const int t = threadIdx.x;
    const int b = blockIdx.z;
    const int n0 = blockIdx.x * 128, o0 = blockIdx.y * 128;
    const int w = t >> 6, l = t & 63;

    f32x4 acc[4][4];
#pragma unroll
    for (int m = 0; m < 4; m++)
#pragma unroll
        for (int n = 0; n < 4; n++) acc[m][n] = (f32x4){0.f, 0.f, 0.f, 0.f};

    const int srow = t >> 2;
    const int scol = (t & 3) * 8;

    int oa0 = o0 + srow, oa1 = o0 + 64 + srow;
    int ra0 = oa0, ra1 = oa1;
    if (rowmap) {
        ra0 = ((oa0 >> 7) << 8) + (((oa0 >> 4) & 7) << 5) + 16 + (oa0 & 15);
        ra1 = ((oa1 >> 7) << 8) + (((oa1 >> 4) & 7) << 5) + 16 + (oa1 & 15);
    }
    const unsigned short* Ag0 = Wb + (long)ra0 * w_ld + scol;
    const unsigned short* Ag1 = Wb + (long)ra1 * w_ld + scol;
    const unsigned short* i1r0 = in1T ? in1T + ((long)b * 4096 + n0 + srow) * 64 + scol : (const unsigned short*)0;
    const unsigned short* i1r1 = in1T ? i1r0 + 64L * 64 : (const unsigned short*)0;
    const unsigned short* i2r0 = in2T + ((long)b * 4096 + n0 + srow) * (long)ld2 + scol;
    const unsigned short* i2r1 = i2r0 + 64L * ld2;

    const int wr = (w >> 1) * 64, wc = (w & 1) * 64;
    const int fr = l & 15, fq = l >> 4;

    for (int kk = 0; kk < K; kk += 32) {
        uint4 av0 = *(const uint4*)(Ag0 + kk);
        uint4 av1 = *(const uint4*)(Ag1 + kk);
        const unsigned short *pb0, *pb1;
        if (kk < c1) { pb0 = i1r0 + kk; pb1 = i1r1 + kk; }
        else         { pb0 = i2r0 + kk; pb1 = i2r1 + kk; }
        uint4 bv0 = *(const uint4*)pb0;
        uint4 bv1 = *(const uint4*)pb1;
        __syncthreads();
        *(uint4*)&Asm[srow * LDP + scol]        = av0;
        *(uint4*)&Asm[(64 + srow) * LDP + scol] = av1;
        *(uint4*)&Bsm[srow * LDP + scol]        = bv0;
        *(uint4*)&Bsm[(64 + srow) * LDP + scol] = bv1;
        __syncthreads();
        bf16x8 af[4], bf[4];
#pragma unroll
        for (int m = 0; m < 4; m++)
            af[m] = *(const bf16x8*)&Asm[(wr + m * 16 + fr) * LDP + fq * 8];
#pragma unroll
        for (int n = 0; n < 4; n++)
            bf[n] = *(const bf16x8*)&Bsm[(wc + n * 16 + fr) * LDP + fq * 8];
#pragma unroll
        for (int m = 0; m < 4; m++)
#pragma unroll
            for (int n = 0; n < 4; n++)
                acc[m][n] = __builtin_amdgcn_mfma_f32_16x16x32_bf16(af[m], bf[n], acc[m][n], 0, 0, 0);
    }

#pragma unroll
    for (int m = 0; m < 4; m++) {
        int ob = o0 + wr + m * 16 + fq * 4;
        float bv[4] = {0.f, 0.f, 0.f, 0.f};
        if (bias) {
#pragma unroll
            for (int r = 0; r < 4; r++) bv[r] = bias[ob + r];
        }
#pragma unroll
        for (int n = 0; n < 4; n++) {
            int ng = n0 + wc + n * 16 + fr;
            float e[4];
#pragma unroll
            for (int r = 0; r < 4; r++) {
                e[r] = acc[m][n][r] + bv[r];
                if (do_gelu) e[r] = gelu_f(e[r]);
            }
            if (addsrc) {
#pragma unroll
                for (int r = 0; r < 4; r++)
                    e[r] += addsrc[(long)b * bsF + (long)(ob + r) * 4096 + ng];
            }
            if (mode == 0 || mode == 2) {
                unsigned short h[4];
#pragma unroll
                for (int r = 0; r < 4; r++) h[r] = f2bf(e[r]);
                uint2 val;
                val.x = h[0] | ((unsigned)h[1] << 16);
                val.y = h[2] | ((unsigned)h[3] << 16);
                *(uint2*)&outT[((long)b * 4096 + ng) * (long)ldo + col_off + ob] = val;
            }
            if (mode == 1 || mode == 2) {
#pragma unroll
                for (int r = 0; r < 4; r++)
                    outF[(long)b * bsF + (long)(ob + r) * 4096 + ng] = e[r];
            }
        }
    }
}

// ---------------------------------------------------------------------------
// MFMA conv: out[pix][oc] = sum_{tap,ic} in[pix+off(tap)][ic] * w[tap][oc][ic]
// Input: token-major bf16, first 64 columns of a row of ld `ldin`.
// Weights: [tap][oc][ic] bf16. Output: token-major bf16 [b][4096][64].
// Block: 128 pixels (2 image rows) x 64 oc; 4 waves = 2 row-waves x 2 oc-waves.
// LDS: haloed token tile [2+2R rows][64+2R px][ICP=40 ic-slots] (zero halo).
// ---------------------------------------------------------------------------
template<int K>
__global__ __launch_bounds__(256) void conv_mfma(
    const unsigned short* __restrict__ inT, int ldin,
    const unsigned short* __restrict__ wb,
    unsigned short* __restrict__ outT)
{
    constexpr int R   = K / 2;
    constexpr int NR  = 2 + 2 * R;
    constexpr int W   = 64 + 2 * R;
    constexpr int ICP = 40;
    __shared__ unsigned short lds[NR * W * ICP];
    const int t = threadIdx.x;
    const int b = blockIdx.y;
    const int y0 = blockIdx.x * 2;
    const int w = t >> 6, l = t & 63;
    const int fr = l & 15, fq = l >> 4;
    const int ocw = (w & 1) * 32;   // oc offset of this wave
    const int rw  = w >> 1;         // which image row of the pair

    f32x4 acc[2][4];
#pragma unroll
    for (int m = 0; m < 2; m++)
#pragma unroll
        for (int j = 0; j < 4; j++) acc[m][j] = (f32x4){0.f, 0.f, 0.f, 0.f};

    for (int kk = 0; kk < 64; kk += 32) {
        __syncthreads();
        for (int e = t; e < NR * W * 4; e += 256) {
            int part = e & 3;
            int px   = (e >> 2) % W;
            int row  = (e >> 2) / W;
            int gx = px - R, gy = y0 - R + row;
            uint4 v = {0u, 0u, 0u, 0u};
            if ((unsigned)gx < 64u && (unsigned)gy < 64u)
                v = *(const uint4*)&inT[((long)b * 4096 + gy * 64 + gx) * (long)ldin + kk + part * 8];
            *(uint4*)&lds[(row * W + px) * ICP + part * 8] = v;
        }
        __syncthreads();
#pragma unroll
        for (int ky = 0; ky < K; ky++) {
#pragma unroll
            for (int kx = 0; kx < K; kx++) {
                const unsigned short* wt = wb + ((long)((ky * K + kx) * 64 + ocw)) * 64 + kk;
                bf16x8 aw0 = *(const bf16x8*)&wt[fr * 64 + fq * 8];
                bf16x8 aw1 = *(const bf16x8*)&wt[(16 + fr) * 64 + fq * 8];
                const unsigned short* lp = &lds[((rw + ky) * W + kx) * ICP + fq * 8];
#pragma unroll
                for (int j = 0; j < 4; j++) {
                    bf16x8 bt = *(const bf16x8*)&lp[(j * 16 + fr) * ICP];
                    acc[0][j] = __builtin_amdgcn_mfma_f32_16x16x32_bf16(aw0, bt, acc[0][j], 0, 0, 0);
                    acc[1][j] = __builtin_amdgcn_mfma_f32_16x16x32_bf16(aw1, bt, acc[1][j], 0, 0, 0);
                }
            }
        }
    }
    // D[m=oc][n=pixel]: oc = ocw + mi*16 + fq*4 + r, pixel = rw*64 + j*16 + fr
    const long tokbase = (long)b * 4096 + (y0 + rw) * 64;
#pragma unroll
    for (int mi = 0; mi < 2; mi++) {
        int oc0 = ocw + mi * 16 + fq * 4;
#pragma unroll
        for (int j = 0; j < 4; j++) {
            long tok = tokbase + j * 16 + fr;
            unsigned short h[4];
#pragma unroll
            for (int r = 0; r < 4; r++) h[r] = f2bf(acc[mi][j][r]);
            uint2 val;
            val.x = h[0] | ((unsigned)h[1] << 16);
            val.y = h[2] | ((unsigned)h[3] << 16);
            *(uint2*)&outT[tok * 64 + oc0] = val;
        }
    }
}

// ---------------------------------------------------------------------------
// Attention (f32, unchanged math): reduce -> mats -> apply.
// ---------------------------------------------------------------------------
#define NC 128
#define ST 132

__global__ __launch_bounds__(256) void attn_reduce(
    const float* __restrict__ qkv, float* __restrict__ part)
{
    const int chunk = blockIdx.x, bh = blockIdx.y;
    const int b = bh >> 3, h = bh & 7;
    const int t = threadIdx.x;

    __shared__ float qch[16][ST], kch[16][ST];
    __shared__ float qfr[9][ST], qfi[9][ST], kfr[9][ST], kfi[9][ST];
    __shared__ float ct[9][16], st_[9][16];

    if (t < 144) {
        int f = t / 16, c = t % 16;
        float ang = 6.283185307179586f * (float)(f * c) / 16.0f;
        ct[f][c] = cosf(ang);
        st_[f][c] = sinf(ang);
    }

    const float* qbase = qkv + (long)b * 1572864 + (long)(16 * h) * 4096;
    const float* kbase = qbase + 128 * 4096;

    float s1 = 0.f, sfr = 0.f, sfi = 0.f;
    float qssp = 0.f, kssp = 0.f, qfssp = 0.f, kfssp = 0.f;
    const int c0 = t >> 4, d0 = t & 15;
    const int cf = t / 9, df = t % 9;
    const int rr = t >> 4, jj0 = t & 15;

    const int nlo = chunk * 512, nhi = nlo + 512;
    for (int n0 = nlo; n0 < nhi; n0 += NC) {
        __syncthreads();
#pragma unroll
        for (int i = 0; i < 8; i++) {
            int e = i * 256 + t, row = e >> 7, nn = e & 127;
            qch[row][nn] = qbase[(long)row * 4096 + n0 + nn];
            kch[row][nn] = kbase[(long)row * 4096 + n0 + nn];
        }
        __syncthreads();
        {
            int col = t & 127;
            bool isq = t < 128;
            float vv[16];
#pragma unroll
            for (int c = 0; c < 16; c++) vv[c] = isq ? qch[c][col] : kch[c][col];
#pragma unroll
            for (int f = 0; f < 9; f++) {
                float ar = 0.f, ai = 0.f;
#pragma unroll
                for (int c = 0; c < 16; c++) { ar += vv[c] * ct[f][c]; ai -= vv[c] * st_[f][c]; }
                if (isq) { qfr[f][col] = ar; qfi[f][col] = ai; }
                else     { kfr[f][col] = ar; kfi[f][col] = ai; }
            }
        }
#pragma unroll 4
        for (int n = 0; n < NC; n++) s1 += qch[c0][n] * kch[d0][n];
        for (int n = jj0; n < NC; n += 16) {
            float a = qch[rr][n]; qssp += a * a;
            float bq = kch[rr][n]; kssp += bq * bq;
        }
        __syncthreads();
        if (t < 81) {
#pragma unroll 4
            for (int n = 0; n < NC; n++) {
                float qr = qfr[cf][n], qi = qfi[cf][n];
                float kr = kfr[df][n], ki = kfi[df][n];
                sfr += qr * kr - qi * ki;
                sfi += qr * ki + qi * kr;
            }
        }
        if (t < 144) {
            int f = t >> 4;
            for (int n = jj0; n < NC; n += 16) {
                qfssp += qfr[f][n] * qfr[f][n] + qfi[f][n] * qfi[f][n];
                kfssp += kfr[f][n] * kfr[f][n] + kfi[f][n] * kfi[f][n];
            }
        }
    }

#pragma unroll
    for (int off = 8; off; off >>= 1) {
        qssp  += __shfl_xor(qssp, off);
        kssp  += __shfl_xor(kssp, off);
        qfssp += __shfl_xor(qfssp, off);
        kfssp += __shfl_xor(kfssp, off);
    }
    float* pb = part + (long)(bh * 8 + chunk) * 512;
    pb[t] = s1;
    if (t < 81) { pb[256 + t] = sfr; pb[337 + t] = sfi; }
    if (jj0 == 0) { pb[448 + rr] = qssp; pb[464 + rr] = kssp; }
    if (jj0 == 0 && t < 144) { pb[480 + rr] = qfssp; pb[489 + rr] = kfssp; }
}

__global__ __launch_bounds__(256) void attn_mats(
    const float* __restrict__ part,
    const float* __restrict__ temp1, const float* __restrict__ temp2,
    const float* __restrict__ tw1, const float* __restrict__ tw2,
    float* __restrict__ amats)
{
    const int bh = blockIdx.x;
    const int h = bh & 7;
    const int t = threadIdx.x;

    __shared__ float S1[256], Sfr[81], Sfi[81];
    __shared__ float qss[16], kss[16], qfss[9], kfss[9];

    float s1 = 0.f, sfr = 0.f, sfi = 0.f, a0 = 0.f, a1 = 0.f, a2 = 0.f, a3 = 0.f;
#pragma unroll
    for (int ch = 0; ch < 8; ch++) {
        const float* p = part + (long)(bh * 8 + ch) * 512;
        s1 += p[t];
        if (t < 81) { sfr += p[256 + t]; sfi += p[337 + t]; }
        if (t < 16) { a0 += p[448 + t]; a1 += p[464 + t]; }
        if (t < 9)  { a2 += p[480 + t]; a3 += p[489 + t]; }
    }
    S1[t] = s1;
    if (t < 81) { Sfr[t] = sfr; Sfi[t] = sfi; }
    if (t < 16) { qss[t] = a0; kss[t] = a1; }
    if (t < 9)  { qfss[t] = a2; kfss[t] = a3; }
    __syncthreads();

    const float t1s = temp1[h], t2s = temp2[h];
    float* am = amats + (long)bh * 448;
    if (t < 16) {
        int c = t;
        float nq = fmaxf(sqrtf(qss[c]), 1e-12f);
        float vals[16];
        float m = -1e30f;
#pragma unroll
        for (int d = 0; d < 16; d++) {
            float nk = fmaxf(sqrtf(kss[d]), 1e-12f);
            float v = S1[c * 16 + d] / (nq * nk) * t1s;
            vals[d] = v; m = fmaxf(m, v);
        }
        float s = 0.f;
#pragma unroll
        for (int d = 0; d < 16; d++) { vals[d] = expf(vals[d] - m); s += vals[d]; }
#pragma unroll
        for (int d = 0; d < 16; d++)
            am[c * 16 + d] = vals[d] / s * tw2[(h * 16 + c) * 16 + d];
    }
    if (t >= 32 && t < 41) {
        int c = t - 32;
        float nq = fmaxf(sqrtf(qfss[c]), 1e-12f);
        float vr[9], vi[9];
        float mr = -1e30f, mi = -1e30f;
#pragma unroll
        for (int d = 0; d < 9; d++) {
            float nk = fmaxf(sqrtf(kfss[d]), 1e-12f);
            float sc = t2s / (nq * nk);
            vr[d] = Sfr[c * 9 + d] * sc; vi[d] = Sfi[c * 9 + d] * sc;
            mr = fmaxf(mr, vr[d]); mi = fmaxf(mi, vi[d]);
        }
        float sr = 0.f, si = 0.f;
#pragma unroll
        for (int d = 0; d < 9; d++) {
            vr[d] = expf(vr[d] - mr); sr += vr[d];
            vi[d] = expf(vi[d] - mi); si += vi[d];
        }
#pragma unroll
        for (int d = 0; d < 9; d++) {
            float tw = tw1[(h * 9 + c) * 9 + d];
            am[256 + c * 9 + d] = vr[d] / sr * tw;
            am[337 + c * 9 + d] = vi[d] / si * tw;
        }
    }
}

__global__ __launch_bounds__(256) void attn_apply(
    const float* __restrict__ qkv, const float* __restrict__ amats,
    unsigned short* __restrict__ axT)
{
    const int chunk = blockIdx.x, bh = blockIdx.y;
    const int b = bh >> 3, h = bh & 7;
    const int t = threadIdx.x;

    __shared__ float attn1[16][16], ar2[9][9], ai2[9][9];
    __shared__ float ct[9][16], st_[9][16];

    const float* am = amats + (long)bh * 448;
    attn1[t >> 4][t & 15] = am[t];
    if (t < 81) { ar2[t / 9][t % 9] = am[256 + t]; ai2[t / 9][t % 9] = am[337 + t]; }
    if (t < 144) {
        int f = t / 16, c = t % 16;
        float ang = 6.283185307179586f * (float)(f * c) / 16.0f;
        ct[f][c] = cosf(ang);
        st_[f][c] = sinf(ang);
    }
    __syncthreads();

    const int col = chunk * 256 + t;
    const float* vbase = qkv + (long)b * 1572864 + (long)(256 + 16 * h) * 4096;

    float vv[16];
#pragma unroll
    for (int c = 0; c < 16; c++) vv[c] = vbase[(long)c * 4096 + col];

    float o1[16];
#pragma unroll
    for (int m = 0; m < 16; m++) {
        float a = 0.f;
#pragma unroll
        for (int d = 0; d < 16; d++) a += attn1[m][d] * vv[d];
        o1[m] = a;
    }
    float vfr[9], vfi[9];
#pragma unroll
    for (int f = 0; f < 9; f++) {
        float ar = 0.f, ai = 0.f;
#pragma unroll
        for (int c = 0; c < 16; c++) { ar += vv[c] * ct[f][c]; ai -= vv[c] * st_[f][c]; }
        vfr[f] = ar; vfi[f] = ai;
    }
    float Lr[9], Li[9];
#pragma unroll
    for (int c = 0; c < 9; c++) {
        float lr = 0.f, li = 0.f;
#pragma unroll
        for (int d = 0; d < 9; d++) {
            lr += ar2[c][d] * vfr[d] - ai2[c][d] * vfi[d];
            li += ar2[c][d] * vfi[d] + ai2[c][d] * vfr[d];
        }
        Lr[c] = lr; Li[c] = li;
    }
    float lx[16];
#pragma unroll
    for (int m = 0; m < 16; m++) {
        float s = Lr[0] + ((m & 1) ? -Lr[8] : Lr[8]);
#pragma unroll
        for (int f = 1; f < 8; f++)
            s += 2.0f * (Lr[f] * ct[f][m] - Li[f] * st_[f][m]);
        lx[m] = s * 0.0625f;
    }
    unsigned short* op = axT + ((long)b * 4096 + col) * 256;
    store8bf(op + 16 * h,       lx);
    store8bf(op + 16 * h + 8,   lx + 8);
    store8bf(op + 128 + 16 * h,     o1);
    store8bf(op + 128 + 16 * h + 8, o1 + 8);
}

// ---------------------------------------------------------------------------
// Host launch
// ---------------------------------------------------------------------------
extern "C" void kernel_launch(void* const* d_in, const int* in_sizes, int n_in,
                              void* d_out, int out_size, void* d_ws, size_t ws_size,
                              hipStream_t stream)
{
    const float* x          = (const float*)d_in[0];
    const float* pc3a_w     = (const float*)d_in[1];
    const float* hm_conv1_w = (const float*)d_in[2];
    const float* hm_proj2_w = (const float*)d_in[3];
    const float* hm_proj2_b = (const float*)d_in[4];
    const float* pc5_w      = (const float*)d_in[5];
    const float* hm_conv2_w = (const float*)d_in[6];
    const float* fuse_w     = (const float*)d_in[7];
    const float* qkv_pc3_w  = (const float*)d_in[8];
    const float* qkv_w      = (const float*)d_in[9];
    const float* proj_w     = (const float*)d_in[10];
    const float* proj_b     = (const float*)d_in[11];
    const float* temp1      = (const float*)d_in[12];
    const float* temp2      = (const float*)d_in[13];
    const float* tw1        = (const float*)d_in[14];
    const float* tw2        = (const float*)d_in[15];
    float* out = (float*)d_out;
    char* wsb  = (char*)d_ws;

    // ---- workspace layout (bytes) ----
    unsigned short* catT  = (unsigned short*)(wsb + 0);          // 100,663,296 (union qkv)
    float*          qkv   = (float*)(wsb + 0);
    unsigned short* xT    = (unsigned short*)(wsb + 100663296);  //  33,554,432 (union axT)
    unsigned short* axT   = (unsigned short*)(wsb + 100663296);
    unsigned short* hxT   = (unsigned short*)(wsb + 134217728);  //  33,554,432
    unsigned short* yT    = (unsigned short*)(wsb + 167772160);  //   8,388,608 (union part/amats)
    float*          part  = (float*)(wsb + 167772160);
    float*          amats = (float*)(wsb + 167772160 + 2097152);
    unsigned short* w1b   = (unsigned short*)(wsb + 176160768);
    unsigned short* w2b   = (unsigned short*)(wsb + 176291840);
    unsigned short* w3b   = (unsigned short*)(wsb + 176422912);
    unsigned short* wfb   = (unsigned short*)(wsb + 176553984);
    unsigned short* wqb   = (unsigned short*)(wsb + 176947200);
    unsigned short* wpb   = (unsigned short*)(wsb + 177340416);
    unsigned short* wc3a  = (unsigned short*)(wsb + 177471488);
    unsigned short* wc5   = (unsigned short*)(wsb + 177545216);
    unsigned short* wc3q  = (unsigned short*)(wsb + 177750016);

    dim3 gg2(32, 2, 16);   // M=256 GEMMs
    dim3 gg3(32, 3, 16);   // M=384 (qkv)
    dim3 cvg(32, 16);      // conv_mfma

    // ---- prep ----
    cvt_bf16<<<256, 256, 0, stream>>>(hm_conv1_w, w1b, 65536);
    cvt_bf16<<<256, 256, 0, stream>>>(hm_proj2_w, w2b, 65536);
    cvt_bf16<<<256, 256, 0, stream>>>(hm_conv2_w, w3b, 65536);
    cvt_bf16<<<768, 256, 0, stream>>>(fuse_w, wfb, 196608);
    cvt_bf16<<<768, 256, 0, stream>>>(qkv_w, wqb, 196608);
    cvt_bf16<<<256, 256, 0, stream>>>(proj_w, wpb, 65536);
    cvt_wconv<<<144, 256, 0, stream>>>(pc3a_w, wc3a, 9);
    cvt_wconv<<<400, 256, 0, stream>>>(pc5_w, wc5, 25);
    cvt_wconv<<<144, 256, 0, stream>>>(qkv_pc3_w, wc3q, 9);
    cvt_xpose<<<dim3(64, 4, 16), 256, 0, stream>>>(x, xT);

    // ---- branch 1: cx = gelu(W1 @ [conv3(x[:64]); x[64:]]) -> catT[:,0:256]
    conv_mfma<3><<<cvg, 256, 0, stream>>>(xT, 256, wc3a, yT);
    mfma_gemm<<<gg2, 256, 0, stream>>>(yT, 64, xT, 256, w1b, 256, 0,
                                       nullptr, nullptr, 256, 0, 1, 0,
                                       catT, 768, nullptr, 0);
    // ---- branch 3: rx = gelu(W3 @ [conv5(x[:64]); x[64:]]) -> catT[:,512:768]
    conv_mfma<5><<<cvg, 256, 0, stream>>>(xT, 256, wc5, yT);
    mfma_gemm<<<gg2, 256, 0, stream>>>(yT, 64, xT, 256, w3b, 256, 0,
                                       nullptr, nullptr, 256, 0, 1, 512,
                                       catT, 768, nullptr, 0);
    // ---- branch 2: px = gelu(W2 @ x + b2) -> catT[:,256:512]
    mfma_gemm<<<gg2, 256, 0, stream>>>(nullptr, 0, xT, 256, w2b, 256, 0,
                                       hm_proj2_b, nullptr, 256, 0, 1, 256,
                                       catT, 768, nullptr, 0);
    // ---- fuse: hxT = fuse_w @ catT + x  (bf16 token-major only)
    mfma_gemm<<<gg2, 256, 0, stream>>>(nullptr, 0, catT, 768, wfb, 768, 0,
                                       nullptr, x, 768, 0, 0, 0,
                                       hxT, 256, nullptr, 1048576L);
    // ---- qkv = qkv_w'[384 rows] @ [conv3(hx[:64]); hx[64:]]  (f32 ch-major)
    conv_mfma<3><<<cvg, 256, 0, stream>>>(hxT, 256, wc3q, yT);
    mfma_gemm<<<gg3, 256, 0, stream>>>(yT, 64, hxT, 256, wqb, 256, 1,
                                       nullptr, nullptr, 256, 1, 0, 0,
                                       nullptr, 0, qkv, 1572864L);
    // ---- attention ----
    attn_reduce<<<dim3(8, 128), 256, 0, stream>>>(qkv, part);
    attn_mats<<<128, 256, 0, stream>>>(part, temp1, temp2, tw1, tw2, amats);
    attn_apply<<<dim3(16, 128), 256, 0, stream>>>(qkv, amats, axT);
    // ---- out = proj_w @ axT + proj_b  (f32 ch-major)
    mfma_gemm<<<gg2, 256, 0, stream>>>(nullptr, 0, axT, 256, wpb, 256, 0,
                                       proj_b, nullptr, 256, 1, 0, 0,
                                       nullptr, 0, out, 1048576L);
}